// Round 1
// baseline (1279.109 us; speedup 1.0000x reference)
//
#include <hip/hip_runtime.h>
#include <math.h>

#define NB 4
#define NC 64
#define NH 48
#define NW 48
#define NHEADS 4
#define NCH 256
#define NHW 2304
#define NBH 16

// ws float offsets
#define OFF_X    0u
#define OFF_Y    589824u
#define OFF_Q    2949120u
#define OFF_K    5308416u
#define OFF_V    7667712u
#define OFF_OH   10027008u
#define OFF_SQ   12386304u
#define OFF_G    12388352u
#define OFF_SC   12519424u

// ---------------- LayerNorm over channel dim ----------------
__global__ __launch_bounds__(64) void k_ln(const float* __restrict__ emb,
                                           const float* __restrict__ lw,
                                           const float* __restrict__ lb,
                                           float* __restrict__ X) {
  int idx = blockIdx.x * 64 + threadIdx.x;   // over NB*NHW positions
  int b = idx / NHW, p = idx % NHW;
  const float* src = emb + (size_t)b * NC * NHW + p;
  float x[64];
  float s = 0.f, ss = 0.f;
#pragma unroll
  for (int c = 0; c < 64; ++c) { float v = src[c * NHW]; x[c] = v; s += v; ss += v * v; }
  float mu = s * (1.f / 64.f);
  float var = ss * (1.f / 64.f) - mu * mu;
  float rstd = rsqrtf(var + 1e-5f);
  float* dst = X + (size_t)b * NC * NHW + p;
#pragma unroll
  for (int c = 0; c < 64; ++c) dst[c * NHW] = (x[c] - mu) * rstd * lw[c] + lb[c];
}

// ---------------- 1x1 conv: Y[o,p] = sum_c W[o,c]*X[c,p] ----------------
__global__ __launch_bounds__(256) void k_conv1x1(const float* __restrict__ X,
                                                 const float* __restrict__ Wm,
                                                 float* __restrict__ Y) {
  // grid: (NHW/64, NB)
  __shared__ float Xs[64][65];
  int b = blockIdx.y;
  int p0 = blockIdx.x * 64;
  const float* src = X + (size_t)b * NC * NHW + p0;
  for (int e = threadIdx.x; e < 64 * 64; e += 256) {
    int c = e >> 6, p = e & 63;
    Xs[c][p] = src[c * NHW + p];
  }
  __syncthreads();
  int pl = threadIdx.x & 63;
  int og = __builtin_amdgcn_readfirstlane(threadIdx.x >> 6);  // wave-uniform
  float xr[64];
#pragma unroll
  for (int c = 0; c < 64; ++c) xr[c] = Xs[c][pl];
  float* dst = Y + (size_t)b * NCH * NHW + p0 + pl;
  const float4* W4 = (const float4*)(Wm + og * 64 * 64);
  for (int oi = 0; oi < 64; ++oi) {
    float acc = 0.f;
#pragma unroll
    for (int c4 = 0; c4 < 16; ++c4) {
      float4 w = W4[oi * 16 + c4];
      acc += w.x * xr[c4 * 4] + w.y * xr[c4 * 4 + 1] + w.z * xr[c4 * 4 + 2] + w.w * xr[c4 * 4 + 3];
    }
    dst[(size_t)(og * 64 + oi) * NHW] = acc;
  }
}

// ---------------- depthwise 3x3 + optional L2-normalize + transpose ----------------
template <bool NORM>
__global__ __launch_bounds__(256) void k_dw(const float* __restrict__ Y,
                                            const float* __restrict__ dw,
                                            float* __restrict__ O) {
  // grid: (NH, NHEADS, NB); block handles one output row h for 64 channels
  __shared__ float Ys[64][3][48];
  __shared__ float Zs[64][49];
  __shared__ float Rs[48];
  int h = blockIdx.x, hd = blockIdx.y, b = blockIdx.z;
  const float* src = Y + ((size_t)b * NCH + hd * 64) * NHW;
  for (int e = threadIdx.x; e < 64 * 3 * 48; e += 256) {
    int c = e / 144, rem = e % 144, r = rem / 48, w = rem % 48;
    int hh = h + r - 1;
    Ys[c][r][w] = (hh >= 0 && hh < NH) ? src[c * NHW + hh * NW + w] : 0.f;
  }
  __syncthreads();
  for (int e = threadIdx.x; e < 64 * 48; e += 256) {
    int c = e / 48, w = e % 48;
    const float* kk = dw + ((size_t)hd * 64 + c) * 9;
    float acc = 0.f;
#pragma unroll
    for (int r = 0; r < 3; ++r)
#pragma unroll
      for (int dx = 0; dx < 3; ++dx) {
        int ww = w + dx - 1;
        float yv = (ww >= 0 && ww < NW) ? Ys[c][r][ww] : 0.f;
        acc += yv * kk[r * 3 + dx];
      }
    Zs[c][w] = acc;
  }
  __syncthreads();
  if (NORM) {
    if (threadIdx.x < 48) {
      int w = threadIdx.x;
      float ss = 0.f;
#pragma unroll
      for (int c = 0; c < 64; ++c) { float z = Zs[c][w]; ss += z * z; }
      Rs[w] = 1.f / fmaxf(sqrtf(ss), 1e-12f);
    }
    __syncthreads();
  }
  float* dst = O + (((size_t)b * NHEADS + hd) * NHW + h * NW) * 64;
  for (int e = threadIdx.x; e < 64 * 48; e += 256) {
    int c = e & 63, w = e >> 6;
    float v = Zs[c][w];
    if (NORM) v *= Rs[w];
    dst[w * 64 + c] = v;
  }
}

// ---------------- partial gram matrices + column sums (atomics) ----------------
__global__ __launch_bounds__(256) void k_gram(const float* __restrict__ Q,
                                              const float* __restrict__ K,
                                              float* __restrict__ SQ,
                                              float* __restrict__ G) {
  // grid: (NHW/128, 2, NBH)
  __shared__ float Xs[128][68];
  int nc = blockIdx.x, qk = blockIdx.y, bh = blockIdx.z;
  const float* src = (qk ? K : Q) + ((size_t)bh * NHW + nc * 128) * 64;
  for (int e = threadIdx.x; e < 128 * 64; e += 256) {
    Xs[e >> 6][e & 63] = src[e];
  }
  __syncthreads();
  if (threadIdx.x < 64) {
    int c = threadIdx.x;
    float s = 0.f;
    for (int n = 0; n < 128; ++n) s += Xs[n][c];
    atomicAdd(&SQ[(bh * 2 + qk) * 64 + c], s);
  }
  int ci0 = (threadIdx.x & 15) * 4, cj0 = (threadIdx.x >> 4) * 4;
  float acc[4][4] = {};
  for (int n = 0; n < 128; ++n) {
    float4 a = *(const float4*)&Xs[n][ci0];
    float4 bb = *(const float4*)&Xs[n][cj0];
    float av[4] = {a.x, a.y, a.z, a.w}, bv[4] = {bb.x, bb.y, bb.z, bb.w};
#pragma unroll
    for (int i = 0; i < 4; ++i)
#pragma unroll
      for (int j = 0; j < 4; ++j) acc[i][j] += av[i] * bv[j];
  }
  float* g = G + (size_t)(bh * 2 + qk) * 4096;
#pragma unroll
  for (int i = 0; i < 4; ++i)
#pragma unroll
    for (int j = 0; j < 4; ++j) atomicAdd(&g[(ci0 + i) * 64 + cj0 + j], acc[i][j]);
}

// ---------------- per-(b,h) softmax scale from stats ----------------
__global__ __launch_bounds__(64) void k_scale(const float* __restrict__ SQ,
                                              const float* __restrict__ G,
                                              float* __restrict__ SC) {
  int bh = blockIdx.x, t = threadIdx.x;
  float sa = SQ[(bh * 2 + 0) * 64 + t] * SQ[(bh * 2 + 1) * 64 + t];
  const float* gq = G + (size_t)(bh * 2 + 0) * 4096;
  const float* gk = G + (size_t)(bh * 2 + 1) * 4096;
  float ssum = 0.f;
  for (int i = t; i < 4096; i += 64) ssum += gq[i] * gk[i];
#pragma unroll
  for (int m = 32; m; m >>= 1) { sa += __shfl_xor(sa, m); ssum += __shfl_xor(ssum, m); }
  if (t == 0) {
    const double N2 = (double)NHW * (double)NHW;
    double mean = (double)sa / (N2 * 48.0);     // mean of atten (= raw/sqrt(num))
    double ea2 = (double)ssum / (N2 * 2304.0);  // E[atten^2]
    double var = ea2 - mean * mean;
    SC[bh] = (float)((1.0 / sqrt(var + 1e-5)) / 48.0);  // applied to raw q.k
  }
}

// ---------------- flash attention (fp32 vector) ----------------
__global__ __launch_bounds__(256) void k_attn(const float* __restrict__ Q,
                                              const float* __restrict__ Kv,
                                              const float* __restrict__ V,
                                              const float* __restrict__ SC,
                                              float* __restrict__ OH) {
  // grid: (NHW/64, NHEADS, NB); block = 4 waves; 64 q-rows per block
  __shared__ float Qs[64][68];
  __shared__ float Ks[64][68];
  __shared__ float Vs[64][68];
  __shared__ float Ss[64][68];
  int qt = blockIdx.x, hd = blockIdx.y, b = blockIdx.z;
  int bh = b * NHEADS + hd;
  size_t base = (size_t)bh * NHW * 64;
  float scale = SC[bh];
  int t = threadIdx.x;
  const float* qsrc = Q + base + (size_t)qt * 64 * 64;
  for (int e = t; e < 4096; e += 256) Qs[e >> 6][e & 63] = qsrc[e];
  int lane = t & 63, wv = t >> 6;
  int tq = t & 15, tm = t >> 4;
  float out_acc[16], mx[16], lsum[16];
#pragma unroll
  for (int r = 0; r < 16; ++r) { out_acc[r] = 0.f; mx[r] = -1e30f; lsum[r] = 0.f; }
  for (int kt = 0; kt < NHW / 64; ++kt) {
    __syncthreads();
    const float* ksrc = Kv + base + (size_t)kt * 64 * 64;
    const float* vsrc = V + base + (size_t)kt * 64 * 64;
    for (int e = t; e < 4096; e += 256) {
      Ks[e >> 6][e & 63] = ksrc[e];
      Vs[e >> 6][e & 63] = vsrc[e];
    }
    __syncthreads();
    // phase 1: S tile = scale * Q K^T  (4x4 per thread)
    float acc[4][4] = {};
#pragma unroll 4
    for (int c4 = 0; c4 < 16; ++c4) {
      float4 qv[4], kv[4];
#pragma unroll
      for (int i = 0; i < 4; ++i) qv[i] = *(const float4*)&Qs[tq * 4 + i][c4 * 4];
#pragma unroll
      for (int j = 0; j < 4; ++j) kv[j] = *(const float4*)&Ks[tm * 4 + j][c4 * 4];
#pragma unroll
      for (int i = 0; i < 4; ++i)
#pragma unroll
        for (int j = 0; j < 4; ++j)
          acc[i][j] += qv[i].x * kv[j].x + qv[i].y * kv[j].y + qv[i].z * kv[j].z + qv[i].w * kv[j].w;
    }
#pragma unroll
    for (int i = 0; i < 4; ++i) {
      float4 sv = make_float4(acc[i][0] * scale, acc[i][1] * scale, acc[i][2] * scale, acc[i][3] * scale);
      *(float4*)&Ss[tq * 4 + i][tm * 4] = sv;
    }
    __syncthreads();
    // phase 2: online softmax + PV, wave wv owns rows wv*16..+15, lane = column c
    int q0 = wv * 16;
#pragma unroll
    for (int r = 0; r < 16; ++r) {
      float sv = Ss[q0 + r][lane];
      float tmaxv = sv;
#pragma unroll
      for (int m = 32; m; m >>= 1) tmaxv = fmaxf(tmaxv, __shfl_xor(tmaxv, m));
      float nm = fmaxf(mx[r], tmaxv);
      float p = __expf(sv - nm);
      float rs = p;
#pragma unroll
      for (int m = 32; m; m >>= 1) rs += __shfl_xor(rs, m);
      float corr = __expf(mx[r] - nm);
      lsum[r] = lsum[r] * corr + rs;
      out_acc[r] *= corr;
      mx[r] = nm;
      Ss[q0 + r][lane] = p;
    }
#pragma unroll 1
    for (int m4 = 0; m4 < 16; ++m4) {
      float vv[4];
#pragma unroll
      for (int j = 0; j < 4; ++j) vv[j] = Vs[m4 * 4 + j][lane];
#pragma unroll
      for (int r = 0; r < 16; ++r) {
        float4 p4 = *(const float4*)&Ss[q0 + r][m4 * 4];
        out_acc[r] += p4.x * vv[0] + p4.y * vv[1] + p4.z * vv[2] + p4.w * vv[3];
      }
    }
  }
  float* dst = OH + base + (size_t)qt * 64 * 64;
  int q0 = wv * 16;
#pragma unroll
  for (int r = 0; r < 16; ++r) dst[(q0 + r) * 64 + lane] = out_acc[r] / lsum[r];
}

// ---------------- head-mean + projection + bias + residual ----------------
__global__ __launch_bounds__(256) void k_proj(const float* __restrict__ OH,
                                              const float* __restrict__ PW,
                                              const float* __restrict__ PB,
                                              const float* __restrict__ org,
                                              float* __restrict__ out) {
  // grid: (NHW/64, NB)
  __shared__ float Ms[64][65];
  int b = blockIdx.y, p0 = blockIdx.x * 64;
  int t = threadIdx.x;
  for (int e = t; e < 4096; e += 256) {
    int pl = e >> 6, ci = e & 63;
    float s = 0.f;
#pragma unroll
    for (int hd = 0; hd < 4; ++hd)
      s += OH[(((size_t)b * NHEADS + hd) * NHW + p0 + pl) * 64 + ci];
    Ms[pl][ci] = 0.25f * s;
  }
  __syncthreads();
  int pl = t & 63;
  int og = __builtin_amdgcn_readfirstlane(t >> 6);
  float xr[64];
#pragma unroll
  for (int ci = 0; ci < 64; ++ci) xr[ci] = Ms[pl][ci];
  const float4* W4 = (const float4*)(PW + og * 16 * 64);
  const float* orgp = org + (size_t)b * NC * NHW + p0 + pl;
  float* outp = out + (size_t)b * NC * NHW + p0 + pl;
  for (int oi = 0; oi < 16; ++oi) {
    int o = og * 16 + oi;
    float acc = PB[o];
#pragma unroll
    for (int c4 = 0; c4 < 16; ++c4) {
      float4 w = W4[oi * 16 + c4];
      acc += w.x * xr[c4 * 4] + w.y * xr[c4 * 4 + 1] + w.z * xr[c4 * 4 + 2] + w.w * xr[c4 * 4 + 3];
    }
    outp[(size_t)o * NHW] = orgp[(size_t)o * NHW] + acc;
  }
}

extern "C" void kernel_launch(void* const* d_in, const int* in_sizes, int n_in,
                              void* d_out, int out_size, void* d_ws, size_t ws_size,
                              hipStream_t stream) {
  const float* emb = (const float*)d_in[0];
  const float* lnw = (const float*)d_in[1];
  const float* lnb = (const float*)d_in[2];
  const float* wq  = (const float*)d_in[3];
  const float* wk  = (const float*)d_in[4];
  const float* wv  = (const float*)d_in[5];
  const float* dwq = (const float*)d_in[6];
  const float* dwk = (const float*)d_in[7];
  const float* dwv = (const float*)d_in[8];
  const float* pw  = (const float*)d_in[9];
  const float* pb  = (const float*)d_in[10];
  float* ws = (float*)d_ws;
  float* X  = ws + OFF_X;
  float* Y  = ws + OFF_Y;
  float* Qb = ws + OFF_Q;
  float* Kb = ws + OFF_K;
  float* Vb = ws + OFF_V;
  float* OH = ws + OFF_OH;
  float* SQ = ws + OFF_SQ;
  float* G  = ws + OFF_G;
  float* SC = ws + OFF_SC;
  float* out = (float*)d_out;

  hipMemsetAsync(SQ, 0, (2048 + 131072) * sizeof(float), stream);
  k_ln<<<dim3(NB * NHW / 64), 64, 0, stream>>>(emb, lnw, lnb, X);
  const float* w1[3] = {wq, wk, wv};
  const float* wd[3] = {dwq, dwk, dwv};
  float* qkv[3] = {Qb, Kb, Vb};
  for (int m = 0; m < 3; ++m) {
    k_conv1x1<<<dim3(NHW / 64, NB), 256, 0, stream>>>(X, w1[m], Y);
    if (m < 2)
      k_dw<true><<<dim3(NH, NHEADS, NB), 256, 0, stream>>>(Y, wd[m], qkv[m]);
    else
      k_dw<false><<<dim3(NH, NHEADS, NB), 256, 0, stream>>>(Y, wd[m], qkv[m]);
  }
  k_gram<<<dim3(NHW / 128, 2, NBH), 256, 0, stream>>>(Qb, Kb, SQ, G);
  k_scale<<<dim3(NBH), 64, 0, stream>>>(SQ, G, SC);
  k_attn<<<dim3(NHW / 64, NHEADS, NB), 256, 0, stream>>>(Qb, Kb, Vb, SC, OH);
  k_proj<<<dim3(NHW / 64, NB), 256, 0, stream>>>(OH, pw, pb, emb, out);
}

// Round 2
// 405.407 us; speedup vs baseline: 3.1551x; 3.1551x over previous
//
#include <hip/hip_runtime.h>
#include <hip/hip_bf16.h>
#include <math.h>

#define NB 4
#define NC 64
#define NH 48
#define NW 48
#define NHEADS 4
#define NCH 256
#define NHW 2304
#define NBH 16

// ws byte offsets
#define OB_X    0ull
#define OB_Y    2359296ull
#define OB_Q    11796480ull
#define OB_K    16515072ull
#define OB_V    21233664ull
#define OB_OH   25952256ull
#define OB_SQ   35389440ull
#define OB_G    35397632ull
#define OB_SC   35921920ull

typedef __bf16 bf16x8 __attribute__((ext_vector_type(8)));
typedef float f32x4 __attribute__((ext_vector_type(4)));

__device__ __forceinline__ float bf2f(ushort u) {
  return __uint_as_float(((unsigned)u) << 16);
}
__device__ __forceinline__ ushort f2bf(float f) {
  __hip_bfloat16 h = __float2bfloat16(f);
  return *(ushort*)&h;
}

// ---------------- LayerNorm over channel dim ----------------
__global__ __launch_bounds__(64) void k_ln(const float* __restrict__ emb,
                                           const float* __restrict__ lw,
                                           const float* __restrict__ lb,
                                           float* __restrict__ X) {
  int idx = blockIdx.x * 64 + threadIdx.x;
  int b = idx / NHW, p = idx % NHW;
  const float* src = emb + (size_t)b * NC * NHW + p;
  float x[64];
  float s = 0.f, ss = 0.f;
#pragma unroll
  for (int c = 0; c < 64; ++c) { float v = src[c * NHW]; x[c] = v; s += v; ss += v * v; }
  float mu = s * (1.f / 64.f);
  float var = ss * (1.f / 64.f) - mu * mu;
  float rstd = rsqrtf(var + 1e-5f);
  float* dst = X + (size_t)b * NC * NHW + p;
#pragma unroll
  for (int c = 0; c < 64; ++c) dst[c * NHW] = (x[c] - mu) * rstd * lw[c] + lb[c];
}

// ---------------- 1x1 conv ----------------
__global__ __launch_bounds__(256) void k_conv1x1(const float* __restrict__ X,
                                                 const float* __restrict__ Wm,
                                                 float* __restrict__ Y) {
  __shared__ float Xs[64][65];
  int b = blockIdx.y;
  int p0 = blockIdx.x * 64;
  const float* src = X + (size_t)b * NC * NHW + p0;
  for (int e = threadIdx.x; e < 64 * 64; e += 256) {
    int c = e >> 6, p = e & 63;
    Xs[c][p] = src[c * NHW + p];
  }
  __syncthreads();
  int pl = threadIdx.x & 63;
  int og = __builtin_amdgcn_readfirstlane(threadIdx.x >> 6);
  float xr[64];
#pragma unroll
  for (int c = 0; c < 64; ++c) xr[c] = Xs[c][pl];
  float* dst = Y + (size_t)b * NCH * NHW + p0 + pl;
  const float4* W4 = (const float4*)(Wm + og * 64 * 64);
  for (int oi = 0; oi < 64; ++oi) {
    float acc = 0.f;
#pragma unroll
    for (int c4 = 0; c4 < 16; ++c4) {
      float4 w = W4[oi * 16 + c4];
      acc += w.x * xr[c4 * 4] + w.y * xr[c4 * 4 + 1] + w.z * xr[c4 * 4 + 2] + w.w * xr[c4 * 4 + 3];
    }
    dst[(size_t)(og * 64 + oi) * NHW] = acc;
  }
}

// ---------------- depthwise 3x3 -> bf16 outputs ----------------
// MODE 0: L2-normalized, row-major [n][64]  (Q, K)
// MODE 1: unnormalized, channel-major [c][n]  (V)
template <int MODE>
__global__ __launch_bounds__(256) void k_dw(const float* __restrict__ Y,
                                            const float* __restrict__ dw,
                                            ushort* __restrict__ O) {
  __shared__ float Ys[64][3][48];
  __shared__ float Zs[64][49];
  __shared__ float Rs[48];
  int h = blockIdx.x, hd = blockIdx.y, b = blockIdx.z;
  int bh = b * NHEADS + hd;
  const float* src = Y + ((size_t)b * NCH + hd * 64) * NHW;
  for (int e = threadIdx.x; e < 64 * 3 * 48; e += 256) {
    int c = e / 144, rem = e % 144, r = rem / 48, w = rem % 48;
    int hh = h + r - 1;
    Ys[c][r][w] = (hh >= 0 && hh < NH) ? src[c * NHW + hh * NW + w] : 0.f;
  }
  __syncthreads();
  for (int e = threadIdx.x; e < 64 * 48; e += 256) {
    int c = e / 48, w = e % 48;
    const float* kk = dw + ((size_t)hd * 64 + c) * 9;
    float acc = 0.f;
#pragma unroll
    for (int r = 0; r < 3; ++r)
#pragma unroll
      for (int dx = 0; dx < 3; ++dx) {
        int ww = w + dx - 1;
        float yv = (ww >= 0 && ww < NW) ? Ys[c][r][ww] : 0.f;
        acc += yv * kk[r * 3 + dx];
      }
    Zs[c][w] = acc;
  }
  __syncthreads();
  if (MODE == 0) {
    if (threadIdx.x < 48) {
      int w = threadIdx.x;
      float ss = 0.f;
#pragma unroll
      for (int c = 0; c < 64; ++c) { float z = Zs[c][w]; ss += z * z; }
      Rs[w] = 1.f / fmaxf(sqrtf(ss), 1e-12f);
    }
    __syncthreads();
    ushort* dst = O + ((size_t)bh * NHW + h * NW) * 64;
    for (int e = threadIdx.x; e < 64 * 48; e += 256) {
      int c = e & 63, w = e >> 6;
      dst[w * 64 + c] = f2bf(Zs[c][w] * Rs[w]);
    }
  } else {
    ushort* dst = O + (size_t)bh * 64 * NHW + h * NW;
    for (int e = threadIdx.x; e < 64 * 48; e += 256) {
      int c = e / 48, w = e % 48;
      dst[(size_t)c * NHW + w] = f2bf(Zs[c][w]);
    }
  }
}

// ---------------- partial gram matrices + column sums (bf16 in) ----------------
__global__ __launch_bounds__(256) void k_gram(const ushort* __restrict__ Q,
                                              const ushort* __restrict__ K,
                                              float* __restrict__ SQ,
                                              float* __restrict__ G) {
  __shared__ float Xs[128][68];
  int nc = blockIdx.x, qk = blockIdx.y, bh = blockIdx.z;
  const ushort* src = (qk ? K : Q) + ((size_t)bh * NHW + nc * 128) * 64;
  for (int e = threadIdx.x; e < 128 * 16; e += 256) {
    ushort4 u = ((const ushort4*)src)[e];
    int base = e * 4, row = base >> 6, col = base & 63;
    Xs[row][col] = bf2f(u.x);
    Xs[row][col + 1] = bf2f(u.y);
    Xs[row][col + 2] = bf2f(u.z);
    Xs[row][col + 3] = bf2f(u.w);
  }
  __syncthreads();
  if (threadIdx.x < 64) {
    int c = threadIdx.x;
    float s = 0.f;
    for (int n = 0; n < 128; ++n) s += Xs[n][c];
    atomicAdd(&SQ[(bh * 2 + qk) * 64 + c], s);
  }
  int ci0 = (threadIdx.x & 15) * 4, cj0 = (threadIdx.x >> 4) * 4;
  float acc[4][4] = {};
  for (int n = 0; n < 128; ++n) {
    float4 a = *(const float4*)&Xs[n][ci0];
    float4 bb = *(const float4*)&Xs[n][cj0];
    float av[4] = {a.x, a.y, a.z, a.w}, bv[4] = {bb.x, bb.y, bb.z, bb.w};
#pragma unroll
    for (int i = 0; i < 4; ++i)
#pragma unroll
      for (int j = 0; j < 4; ++j) acc[i][j] += av[i] * bv[j];
  }
  float* g = G + (size_t)(bh * 2 + qk) * 4096;
#pragma unroll
  for (int i = 0; i < 4; ++i)
#pragma unroll
    for (int j = 0; j < 4; ++j) atomicAdd(&g[(ci0 + i) * 64 + cj0 + j], acc[i][j]);
}

// ---------------- per-(b,h) softmax scale from stats ----------------
__global__ __launch_bounds__(64) void k_scale(const float* __restrict__ SQ,
                                              const float* __restrict__ G,
                                              float* __restrict__ SC) {
  int bh = blockIdx.x, t = threadIdx.x;
  float sa = SQ[(bh * 2 + 0) * 64 + t] * SQ[(bh * 2 + 1) * 64 + t];
  const float* gq = G + (size_t)(bh * 2 + 0) * 4096;
  const float* gk = G + (size_t)(bh * 2 + 1) * 4096;
  float ssum = 0.f;
  for (int i = t; i < 4096; i += 64) ssum += gq[i] * gk[i];
#pragma unroll
  for (int m = 32; m; m >>= 1) { sa += __shfl_xor(sa, m); ssum += __shfl_xor(ssum, m); }
  if (t == 0) {
    const double N2 = (double)NHW * (double)NHW;
    double mean = (double)sa / (N2 * 48.0);
    double ea2 = (double)ssum / (N2 * 2304.0);
    double var = ea2 - mean * mean;
    SC[bh] = (float)((1.0 / sqrt(var + 1e-5)) / 48.0);
  }
}

// ---------------- flash attention (bf16 MFMA) ----------------
// grid: (36, NHEADS, NB), 4 waves. Each wave owns 16 q-rows.
// Frag layouts (mfma_f32_16x16x32_bf16):
//   A/B: lane l -> row/col (l&15), k = (l>>4)*8+j (contiguous 8 bf16)
//   C/D: col = lane&15, row = (lane>>4)*4 + reg
__global__ __launch_bounds__(256) void k_attn(const ushort* __restrict__ Q,
                                              const ushort* __restrict__ K,
                                              const ushort* __restrict__ V,
                                              const float* __restrict__ SC,
                                              float* __restrict__ OH) {
  __shared__ ushort Ks[64][72];
  __shared__ ushort Vs[64][72];   // Vs[c][m]
  __shared__ ushort Ps[64][72];   // Ps[q][m], per-wave 16-row regions
  int qt = blockIdx.x, hd = blockIdx.y, b = blockIdx.z;
  int bh = b * NHEADS + hd;
  size_t basen = (size_t)bh * NHW;
  float scale = SC[bh];
  int t = threadIdx.x, lane = t & 63, wv = t >> 6;
  int lr = lane & 15, lg = lane >> 4;
  int q0w = wv * 16;

  bf16x8 qa[2];
  {
    const ushort* qp = Q + (basen + (size_t)qt * 64 + q0w + lr) * 64 + lg * 8;
    qa[0] = *(const bf16x8*)(qp);
    qa[1] = *(const bf16x8*)(qp + 32);
  }
  f32x4 o[4];
  float m_run[4], l_run[4];
#pragma unroll
  for (int i = 0; i < 4; ++i) {
    o[i] = (f32x4){0.f, 0.f, 0.f, 0.f};
    m_run[i] = -1e30f;
    l_run[i] = 0.f;
  }

  for (int kt = 0; kt < NHW / 64; ++kt) {
    __syncthreads();
    {
      const ushort* kp = K + (basen + (size_t)kt * 64) * 64;
      const ushort* vp = V + (size_t)bh * 64 * NHW + (size_t)kt * 64;
#pragma unroll
      for (int it = 0; it < 2; ++it) {
        int idx = t + it * 256;          // 0..511
        int row = idx >> 3, g = (idx & 7) * 8;
        *(bf16x8*)&Ks[row][g] = *(const bf16x8*)&kp[row * 64 + g];
        *(bf16x8*)&Vs[row][g] = *(const bf16x8*)&vp[(size_t)row * NHW + g];
      }
    }
    __syncthreads();
    // S = scale * Q K^T  (4 column tiles of 16)
    f32x4 s[4];
#pragma unroll
    for (int mt = 0; mt < 4; ++mt) {
      bf16x8 kb0 = *(const bf16x8*)&Ks[mt * 16 + lr][lg * 8];
      bf16x8 kb1 = *(const bf16x8*)&Ks[mt * 16 + lr][lg * 8 + 32];
      f32x4 acc = (f32x4){0.f, 0.f, 0.f, 0.f};
      acc = __builtin_amdgcn_mfma_f32_16x16x32_bf16(qa[0], kb0, acc, 0, 0, 0);
      acc = __builtin_amdgcn_mfma_f32_16x16x32_bf16(qa[1], kb1, acc, 0, 0, 0);
      s[mt] = acc * scale;
    }
    // online softmax (rows handled per-lane: row = lg*4 + r)
#pragma unroll
    for (int r = 0; r < 4; ++r) {
      float tm = fmaxf(fmaxf(s[0][r], s[1][r]), fmaxf(s[2][r], s[3][r]));
      tm = fmaxf(tm, __shfl_xor(tm, 1));
      tm = fmaxf(tm, __shfl_xor(tm, 2));
      tm = fmaxf(tm, __shfl_xor(tm, 4));
      tm = fmaxf(tm, __shfl_xor(tm, 8));
      float mn = fmaxf(m_run[r], tm);
      float corr = __expf(m_run[r] - mn);
      m_run[r] = mn;
      float rs = 0.f;
#pragma unroll
      for (int mt = 0; mt < 4; ++mt) {
        float pv = __expf(s[mt][r] - mn);
        s[mt][r] = pv;
        rs += pv;
      }
      rs += __shfl_xor(rs, 1);
      rs += __shfl_xor(rs, 2);
      rs += __shfl_xor(rs, 4);
      rs += __shfl_xor(rs, 8);
      l_run[r] = l_run[r] * corr + rs;
      o[0][r] *= corr; o[1][r] *= corr; o[2][r] *= corr; o[3][r] *= corr;
    }
    // P -> LDS (bf16), per-wave region
#pragma unroll
    for (int mt = 0; mt < 4; ++mt)
#pragma unroll
      for (int r = 0; r < 4; ++r)
        Ps[q0w + lg * 4 + r][mt * 16 + lr] = f2bf(s[mt][r]);
    // O += P V
#pragma unroll
    for (int ks = 0; ks < 2; ++ks) {
      bf16x8 pa = *(const bf16x8*)&Ps[q0w + lr][lg * 8 + ks * 32];
#pragma unroll
      for (int ct = 0; ct < 4; ++ct) {
        bf16x8 vb = *(const bf16x8*)&Vs[ct * 16 + lr][lg * 8 + ks * 32];
        o[ct] = __builtin_amdgcn_mfma_f32_16x16x32_bf16(pa, vb, o[ct], 0, 0, 0);
      }
    }
  }
  float* dst = OH + (basen + (size_t)qt * 64 + q0w) * 64;
#pragma unroll
  for (int r = 0; r < 4; ++r) {
    float inv = 1.f / l_run[r];
#pragma unroll
    for (int ct = 0; ct < 4; ++ct)
      dst[(lg * 4 + r) * 64 + ct * 16 + lr] = o[ct][r] * inv;
  }
}

// ---------------- head-mean + projection + bias + residual ----------------
__global__ __launch_bounds__(256) void k_proj(const float* __restrict__ OH,
                                              const float* __restrict__ PW,
                                              const float* __restrict__ PB,
                                              const float* __restrict__ org,
                                              float* __restrict__ out) {
  __shared__ float Ms[64][65];
  int b = blockIdx.y, p0 = blockIdx.x * 64;
  int t = threadIdx.x;
  for (int e = t; e < 4096; e += 256) {
    int pl = e >> 6, ci = e & 63;
    float s = 0.f;
#pragma unroll
    for (int hd = 0; hd < 4; ++hd)
      s += OH[(((size_t)b * NHEADS + hd) * NHW + p0 + pl) * 64 + ci];
    Ms[pl][ci] = 0.25f * s;
  }
  __syncthreads();
  int pl = t & 63;
  int og = __builtin_amdgcn_readfirstlane(t >> 6);
  float xr[64];
#pragma unroll
  for (int ci = 0; ci < 64; ++ci) xr[ci] = Ms[pl][ci];
  const float4* W4 = (const float4*)(PW + og * 16 * 64);
  const float* orgp = org + (size_t)b * NC * NHW + p0 + pl;
  float* outp = out + (size_t)b * NC * NHW + p0 + pl;
  for (int oi = 0; oi < 16; ++oi) {
    int o = og * 16 + oi;
    float acc = PB[o];
#pragma unroll
    for (int c4 = 0; c4 < 16; ++c4) {
      float4 w = W4[oi * 16 + c4];
      acc += w.x * xr[c4 * 4] + w.y * xr[c4 * 4 + 1] + w.z * xr[c4 * 4 + 2] + w.w * xr[c4 * 4 + 3];
    }
    outp[(size_t)o * NHW] = orgp[(size_t)o * NHW] + acc;
  }
}

extern "C" void kernel_launch(void* const* d_in, const int* in_sizes, int n_in,
                              void* d_out, int out_size, void* d_ws, size_t ws_size,
                              hipStream_t stream) {
  const float* emb = (const float*)d_in[0];
  const float* lnw = (const float*)d_in[1];
  const float* lnb = (const float*)d_in[2];
  const float* wq  = (const float*)d_in[3];
  const float* wk  = (const float*)d_in[4];
  const float* wv  = (const float*)d_in[5];
  const float* dwq = (const float*)d_in[6];
  const float* dwk = (const float*)d_in[7];
  const float* dwv = (const float*)d_in[8];
  const float* pw  = (const float*)d_in[9];
  const float* pb  = (const float*)d_in[10];
  char* ws = (char*)d_ws;
  float*  X   = (float*)(ws + OB_X);
  float*  Y   = (float*)(ws + OB_Y);
  ushort* Qb  = (ushort*)(ws + OB_Q);
  ushort* Kb  = (ushort*)(ws + OB_K);
  ushort* Vb  = (ushort*)(ws + OB_V);
  float*  OH  = (float*)(ws + OB_OH);
  float*  SQ  = (float*)(ws + OB_SQ);
  float*  G   = (float*)(ws + OB_G);
  float*  SCp = (float*)(ws + OB_SC);
  float* out = (float*)d_out;

  hipMemsetAsync(SQ, 0, (2048 + 131072) * sizeof(float), stream);
  k_ln<<<dim3(NB * NHW / 64), 64, 0, stream>>>(emb, lnw, lnb, X);

  k_conv1x1<<<dim3(NHW / 64, NB), 256, 0, stream>>>(X, wq, Y);
  k_dw<0><<<dim3(NH, NHEADS, NB), 256, 0, stream>>>(Y, dwq, Qb);
  k_conv1x1<<<dim3(NHW / 64, NB), 256, 0, stream>>>(X, wk, Y);
  k_dw<0><<<dim3(NH, NHEADS, NB), 256, 0, stream>>>(Y, dwk, Kb);
  k_conv1x1<<<dim3(NHW / 64, NB), 256, 0, stream>>>(X, wv, Y);
  k_dw<1><<<dim3(NH, NHEADS, NB), 256, 0, stream>>>(Y, dwv, Vb);

  k_gram<<<dim3(NHW / 128, 2, NBH), 256, 0, stream>>>(Qb, Kb, SQ, G);
  k_scale<<<dim3(NBH), 64, 0, stream>>>(SQ, G, SCp);
  k_attn<<<dim3(NHW / 64, NHEADS, NB), 256, 0, stream>>>(Qb, Kb, Vb, SCp, OH);
  k_proj<<<dim3(NHW / 64, NB), 256, 0, stream>>>(OH, pw, pb, emb, out);
}

// Round 3
// 222.793 us; speedup vs baseline: 5.7413x; 1.8197x over previous
//
#include <hip/hip_runtime.h>
#include <hip/hip_bf16.h>
#include <math.h>

#define NB 4
#define NC 64
#define NH 48
#define NW 48
#define NHEADS 4
#define NCH 256
#define NHW 2304
#define NBH 16
#define NCHK 2
#define CHUNK 1152

// ws byte offsets
#define OB_Y    0ull          // bf16 [3][NB][NCH][NHW] = 14,155,776 (dead after k_dw)
#define OB_OHP  0ull          // f32 [NCHK][NBH][NHW][64] = 18,874,368 (overlaps Y; lifetimes disjoint)
#define OB_Q    18874368ull   // bf16 [NBH][NHW][64]
#define OB_K    23592960ull
#define OB_V    28311552ull   // bf16 [NBH][64][NHW]
#define OB_L    33030144ull   // f32 [NCHK][NBH][NHW] = 294,912
#define OB_SQ   33325056ull   // 8,192
#define OB_G    33333248ull   // 524,288
#define OB_SC   33857536ull

typedef __bf16 bf16x8 __attribute__((ext_vector_type(8)));
typedef float f32x4 __attribute__((ext_vector_type(4)));

__device__ __forceinline__ float bf2f(ushort u) {
  return __uint_as_float(((unsigned)u) << 16);
}
__device__ __forceinline__ ushort f2bf(float f) {
  __hip_bfloat16 h = __float2bfloat16(f);
  return *(ushort*)&h;
}

// ---------------- fused LayerNorm + 1x1 conv (q/k/v via grid.z), bf16 out ----------------
__global__ __launch_bounds__(256) void k_lnconv(const float* __restrict__ emb,
                                                const float* __restrict__ lw,
                                                const float* __restrict__ lb,
                                                const float* __restrict__ wq,
                                                const float* __restrict__ wk,
                                                const float* __restrict__ wv,
                                                ushort* __restrict__ Y) {
  __shared__ float Xs[64][65];
  __shared__ float mu_s[64], rs_s[64];
  int p0 = blockIdx.x * 64, b = blockIdx.y, qkv = blockIdx.z;
  const float* Wm = qkv == 0 ? wq : (qkv == 1 ? wk : wv);
  const float* src = emb + (size_t)b * NC * NHW + p0;
  for (int e = threadIdx.x; e < 1024; e += 256) {
    int c = e >> 4, p4 = (e & 15) * 4;
    *(float4*)&Xs[c][p4] = *(const float4*)&src[c * NHW + p4];
  }
  __syncthreads();
  if (threadIdx.x < 64) {
    int p = threadIdx.x;
    float s = 0.f, ss = 0.f;
#pragma unroll
    for (int c = 0; c < 64; ++c) { float v = Xs[c][p]; s += v; ss += v * v; }
    float m = s * (1.f / 64.f), v = ss * (1.f / 64.f) - m * m;
    mu_s[p] = m;
    rs_s[p] = rsqrtf(v + 1e-5f);
  }
  __syncthreads();
  int pl = threadIdx.x & 63;
  int og = __builtin_amdgcn_readfirstlane(threadIdx.x >> 6);
  float mu = mu_s[pl], rs = rs_s[pl];
  float xr[64];
#pragma unroll
  for (int c = 0; c < 64; ++c) xr[c] = (Xs[c][pl] - mu) * rs * lw[c] + lb[c];
  ushort* dst = Y + ((size_t)(qkv * NB + b) * NCH + og * 64) * NHW + p0 + pl;
  const float4* W4 = (const float4*)(Wm + og * 64 * 64);
  for (int oi = 0; oi < 64; ++oi) {
    float acc = 0.f;
#pragma unroll
    for (int c4 = 0; c4 < 16; ++c4) {
      float4 w = W4[oi * 16 + c4];
      acc += w.x * xr[c4 * 4] + w.y * xr[c4 * 4 + 1] + w.z * xr[c4 * 4 + 2] + w.w * xr[c4 * 4 + 3];
    }
    dst[(size_t)oi * NHW] = f2bf(acc);
  }
}

// ---------------- depthwise 3x3 (q/k/v merged via grid.y), bf16 in/out ----------------
__global__ __launch_bounds__(256) void k_dw(const ushort* __restrict__ Y,
                                            const float* __restrict__ dwq,
                                            const float* __restrict__ dwk,
                                            const float* __restrict__ dwv,
                                            ushort* __restrict__ Qo,
                                            ushort* __restrict__ Ko,
                                            ushort* __restrict__ Vo) {
  __shared__ ushort Ys[64][3][48];
  __shared__ float Zs[64][49];
  __shared__ float Rs[48];
  int h = blockIdx.x;
  int hd = blockIdx.y & 3, qkv = blockIdx.y >> 2;
  int b = blockIdx.z;
  int bh = b * NHEADS + hd;
  const float* dwp = qkv == 0 ? dwq : (qkv == 1 ? dwk : dwv);
  const ushort* src = Y + ((size_t)(qkv * NB + b) * NCH + hd * 64) * NHW;
  for (int e = threadIdx.x; e < 64 * 3 * 12; e += 256) {
    int c = e / 36, rem = e % 36, r = rem / 12, w4 = (rem % 12) * 4;
    int hh = h + r - 1;
    ushort4 v = (hh >= 0 && hh < NH) ? *(const ushort4*)&src[c * NHW + hh * NW + w4]
                                     : make_ushort4(0, 0, 0, 0);
    *(ushort4*)&Ys[c][r][w4] = v;
  }
  __syncthreads();
  for (int e = threadIdx.x; e < 64 * 48; e += 256) {
    int c = e / 48, w = e % 48;
    const float* kk = dwp + ((size_t)hd * 64 + c) * 9;
    float acc = 0.f;
#pragma unroll
    for (int r = 0; r < 3; ++r)
#pragma unroll
      for (int dx = 0; dx < 3; ++dx) {
        int ww = w + dx - 1;
        float yv = (ww >= 0 && ww < NW) ? bf2f(Ys[c][r][ww]) : 0.f;
        acc += yv * kk[r * 3 + dx];
      }
    Zs[c][w] = acc;
  }
  __syncthreads();
  if (qkv < 2) {
    if (threadIdx.x < 48) {
      int w = threadIdx.x;
      float ss = 0.f;
#pragma unroll
      for (int c = 0; c < 64; ++c) { float z = Zs[c][w]; ss += z * z; }
      Rs[w] = 1.f / fmaxf(sqrtf(ss), 1e-12f);
    }
    __syncthreads();
    ushort* dst = (qkv == 0 ? Qo : Ko) + ((size_t)bh * NHW + h * NW) * 64;
    for (int e = threadIdx.x; e < 48 * 16; e += 256) {
      int w = e >> 4, c4 = (e & 15) * 4;
      float rsc = Rs[w];
      ushort4 u = make_ushort4(f2bf(Zs[c4][w] * rsc), f2bf(Zs[c4 + 1][w] * rsc),
                               f2bf(Zs[c4 + 2][w] * rsc), f2bf(Zs[c4 + 3][w] * rsc));
      *(ushort4*)&dst[w * 64 + c4] = u;
    }
  } else {
    ushort* dst = Vo + (size_t)bh * 64 * NHW + h * NW;
    for (int e = threadIdx.x; e < 64 * 12; e += 256) {
      int c = e / 12, w4 = (e % 12) * 4;
      ushort4 u = make_ushort4(f2bf(Zs[c][w4]), f2bf(Zs[c][w4 + 1]),
                               f2bf(Zs[c][w4 + 2]), f2bf(Zs[c][w4 + 3]));
      *(ushort4*)&dst[(size_t)c * NHW + w4] = u;
    }
  }
}

// ---------------- partial gram matrices + column sums ----------------
__global__ __launch_bounds__(256) void k_gram(const ushort* __restrict__ Q,
                                              const ushort* __restrict__ K,
                                              float* __restrict__ SQ,
                                              float* __restrict__ G) {
  __shared__ float Xs[128][68];
  int nc = blockIdx.x, qk = blockIdx.y, bh = blockIdx.z;
  const ushort* src = (qk ? K : Q) + ((size_t)bh * NHW + nc * 128) * 64;
  for (int e = threadIdx.x; e < 128 * 16; e += 256) {
    ushort4 u = ((const ushort4*)src)[e];
    int base = e * 4, row = base >> 6, col = base & 63;
    Xs[row][col] = bf2f(u.x);
    Xs[row][col + 1] = bf2f(u.y);
    Xs[row][col + 2] = bf2f(u.z);
    Xs[row][col + 3] = bf2f(u.w);
  }
  __syncthreads();
  if (threadIdx.x < 64) {
    int c = threadIdx.x;
    float s = 0.f;
    for (int n = 0; n < 128; ++n) s += Xs[n][c];
    atomicAdd(&SQ[(bh * 2 + qk) * 64 + c], s);
  }
  int ci0 = (threadIdx.x & 15) * 4, cj0 = (threadIdx.x >> 4) * 4;
  float acc[4][4] = {};
  for (int n = 0; n < 128; ++n) {
    float4 a = *(const float4*)&Xs[n][ci0];
    float4 bb = *(const float4*)&Xs[n][cj0];
    float av[4] = {a.x, a.y, a.z, a.w}, bv[4] = {bb.x, bb.y, bb.z, bb.w};
#pragma unroll
    for (int i = 0; i < 4; ++i)
#pragma unroll
      for (int j = 0; j < 4; ++j) acc[i][j] += av[i] * bv[j];
  }
  float* g = G + (size_t)(bh * 2 + qk) * 4096;
#pragma unroll
  for (int i = 0; i < 4; ++i)
#pragma unroll
    for (int j = 0; j < 4; ++j) atomicAdd(&g[(ci0 + i) * 64 + cj0 + j], acc[i][j]);
}

// ---------------- per-(b,h) softmax scale ----------------
__global__ __launch_bounds__(64) void k_scale(const float* __restrict__ SQ,
                                              const float* __restrict__ G,
                                              float* __restrict__ SC) {
  int bh = blockIdx.x, t = threadIdx.x;
  float sa = SQ[(bh * 2 + 0) * 64 + t] * SQ[(bh * 2 + 1) * 64 + t];
  const float* gq = G + (size_t)(bh * 2 + 0) * 4096;
  const float* gk = G + (size_t)(bh * 2 + 1) * 4096;
  float ssum = 0.f;
  for (int i = t; i < 4096; i += 64) ssum += gq[i] * gk[i];
#pragma unroll
  for (int m = 32; m; m >>= 1) { sa += __shfl_xor(sa, m); ssum += __shfl_xor(ssum, m); }
  if (t == 0) {
    const double N2 = (double)NHW * (double)NHW;
    double mean = (double)sa / (N2 * 48.0);
    double ea2 = (double)ssum / (N2 * 2304.0);
    double var = ea2 - mean * mean;
    SC[bh] = (float)((1.0 / sqrt(var + 1e-5)) / 48.0);
  }
}

// ---------------- flash attention v3: swapped QK^T, no-max softmax, KV-split ----------------
// grid (18, NCHK, NBH), 4 waves; wave owns 32 q-rows; |S| <= ~6.7 so exp is overflow-safe.
__global__ __launch_bounds__(256) void k_attn(const ushort* __restrict__ Q,
                                              const ushort* __restrict__ K,
                                              const ushort* __restrict__ V,
                                              const float* __restrict__ SC,
                                              float* __restrict__ OHp,
                                              float* __restrict__ Lp) {
  __shared__ ushort Ks[64][72];
  __shared__ ushort Vs[64][72];    // Vs[c][m]
  __shared__ ushort Ps[128][72];   // per-wave 32-row regions
  int qt = blockIdx.x, chunk = blockIdx.y, bh = blockIdx.z;
  size_t basen = (size_t)bh * NHW;
  float scale = SC[bh];
  int t = threadIdx.x, lane = t & 63, wv = t >> 6;
  int lr = lane & 15, lg = lane >> 4;
  int q0 = qt * 128 + wv * 32;
  int m0 = chunk * CHUNK;

  bf16x8 qb[2][2];
#pragma unroll
  for (int qh = 0; qh < 2; ++qh)
#pragma unroll
    for (int ks = 0; ks < 2; ++ks)
      qb[qh][ks] = *(const bf16x8*)&Q[(basen + q0 + qh * 16 + lr) * 64 + ks * 32 + lg * 8];

  f32x4 o[2][4];
  float lp[2] = {0.f, 0.f};
#pragma unroll
  for (int qh = 0; qh < 2; ++qh)
#pragma unroll
    for (int ct = 0; ct < 4; ++ct) o[qh][ct] = (f32x4){0.f, 0.f, 0.f, 0.f};

  for (int kt = 0; kt < CHUNK / 64; ++kt) {
    __syncthreads();
    {
      const ushort* kp = K + (basen + m0 + kt * 64) * 64;
      const ushort* vp = V + (size_t)bh * 64 * NHW + m0 + kt * 64;
#pragma unroll
      for (int it = 0; it < 2; ++it) {
        int idx = t + it * 256;
        int row = idx >> 3, g = (idx & 7) * 8;
        *(bf16x8*)&Ks[row][g] = *(const bf16x8*)&kp[row * 64 + g];
        *(bf16x8*)&Vs[row][g] = *(const bf16x8*)&vp[(size_t)row * NHW + g];
      }
    }
    __syncthreads();
    // S^T = K Q^T (per 16-row K subtile), P = exp(S*scale), pack -> Ps
#pragma unroll
    for (int mt = 0; mt < 4; ++mt) {
      bf16x8 ka0 = *(const bf16x8*)&Ks[mt * 16 + lr][lg * 8];
      bf16x8 ka1 = *(const bf16x8*)&Ks[mt * 16 + lr][lg * 8 + 32];
#pragma unroll
      for (int qh = 0; qh < 2; ++qh) {
        f32x4 acc = (f32x4){0.f, 0.f, 0.f, 0.f};
        acc = __builtin_amdgcn_mfma_f32_16x16x32_bf16(ka0, qb[qh][0], acc, 0, 0, 0);
        acc = __builtin_amdgcn_mfma_f32_16x16x32_bf16(ka1, qb[qh][1], acc, 0, 0, 0);
        float p0 = __expf(acc[0] * scale);
        float p1 = __expf(acc[1] * scale);
        float p2 = __expf(acc[2] * scale);
        float p3 = __expf(acc[3] * scale);
        lp[qh] += (p0 + p1) + (p2 + p3);
        uint u0 = (uint)f2bf(p0) | ((uint)f2bf(p1) << 16);
        uint u1 = (uint)f2bf(p2) | ((uint)f2bf(p3) << 16);
        *(uint2*)&Ps[wv * 32 + qh * 16 + lr][mt * 16 + lg * 4] = make_uint2(u0, u1);
      }
    }
    // O += P V
#pragma unroll
    for (int ks = 0; ks < 2; ++ks) {
      bf16x8 vb[4];
#pragma unroll
      for (int ct = 0; ct < 4; ++ct)
        vb[ct] = *(const bf16x8*)&Vs[ct * 16 + lr][lg * 8 + ks * 32];
#pragma unroll
      for (int qh = 0; qh < 2; ++qh) {
        bf16x8 pa = *(const bf16x8*)&Ps[wv * 32 + qh * 16 + lr][lg * 8 + ks * 32];
#pragma unroll
        for (int ct = 0; ct < 4; ++ct)
          o[qh][ct] = __builtin_amdgcn_mfma_f32_16x16x32_bf16(pa, vb[ct], o[qh][ct], 0, 0, 0);
      }
    }
  }
#pragma unroll
  for (int qh = 0; qh < 2; ++qh) {
    lp[qh] += __shfl_xor(lp[qh], 16);
    lp[qh] += __shfl_xor(lp[qh], 32);
  }
  if (lg == 0) {
#pragma unroll
    for (int qh = 0; qh < 2; ++qh)
      Lp[(size_t)(chunk * NBH + bh) * NHW + q0 + qh * 16 + lr] = lp[qh];
  }
  float* dst = OHp + ((size_t)(chunk * NBH + bh) * NHW + q0) * 64;
#pragma unroll
  for (int qh = 0; qh < 2; ++qh)
#pragma unroll
    for (int r = 0; r < 4; ++r)
#pragma unroll
      for (int ct = 0; ct < 4; ++ct)
        dst[(qh * 16 + lg * 4 + r) * 64 + ct * 16 + lr] = o[qh][ct][r];
}

// ---------------- combine partials + head-mean + projection + residual ----------------
__global__ __launch_bounds__(256) void k_proj(const float* __restrict__ OHp,
                                              const float* __restrict__ Lp,
                                              const float* __restrict__ PW,
                                              const float* __restrict__ PB,
                                              const float* __restrict__ org,
                                              float* __restrict__ out) {
  __shared__ float Ms[64][65];
  __shared__ float linv[4][64];
  int b = blockIdx.y, p0 = blockIdx.x * 64;
  int t = threadIdx.x;
  {
    int hd = t >> 6, pl = t & 63;
    int bh = b * 4 + hd;
    float l0 = Lp[(size_t)bh * NHW + p0 + pl];
    float l1 = Lp[(size_t)(NBH + bh) * NHW + p0 + pl];
    linv[hd][pl] = 1.f / (l0 + l1);
  }
  __syncthreads();
  for (int e = t; e < 4096; e += 256) {
    int pl = e >> 6, ci = e & 63;
    float s = 0.f;
#pragma unroll
    for (int hd = 0; hd < 4; ++hd) {
      size_t i0 = ((size_t)(b * 4 + hd) * NHW + p0 + pl) * 64 + ci;
      float ov = OHp[i0] + OHp[(size_t)NBH * NHW * 64 + i0];
      s += ov * linv[hd][pl];
    }
    Ms[pl][ci] = 0.25f * s;
  }
  __syncthreads();
  int pl = t & 63;
  int og = __builtin_amdgcn_readfirstlane(t >> 6);
  float xr[64];
#pragma unroll
  for (int ci = 0; ci < 64; ++ci) xr[ci] = Ms[pl][ci];
  const float4* W4 = (const float4*)(PW + og * 16 * 64);
  const float* orgp = org + (size_t)b * NC * NHW + p0 + pl;
  float* outp = out + (size_t)b * NC * NHW + p0 + pl;
  for (int oi = 0; oi < 16; ++oi) {
    int oc = og * 16 + oi;
    float acc = PB[oc];
#pragma unroll
    for (int c4 = 0; c4 < 16; ++c4) {
      float4 w = W4[oi * 16 + c4];
      acc += w.x * xr[c4 * 4] + w.y * xr[c4 * 4 + 1] + w.z * xr[c4 * 4 + 2] + w.w * xr[c4 * 4 + 3];
    }
    outp[(size_t)oc * NHW] = orgp[(size_t)oc * NHW] + acc;
  }
}

extern "C" void kernel_launch(void* const* d_in, const int* in_sizes, int n_in,
                              void* d_out, int out_size, void* d_ws, size_t ws_size,
                              hipStream_t stream) {
  const float* emb = (const float*)d_in[0];
  const float* lnw = (const float*)d_in[1];
  const float* lnb = (const float*)d_in[2];
  const float* wq  = (const float*)d_in[3];
  const float* wk  = (const float*)d_in[4];
  const float* wv  = (const float*)d_in[5];
  const float* dwq = (const float*)d_in[6];
  const float* dwk = (const float*)d_in[7];
  const float* dwv = (const float*)d_in[8];
  const float* pw  = (const float*)d_in[9];
  const float* pb  = (const float*)d_in[10];
  char* ws = (char*)d_ws;
  ushort* Y   = (ushort*)(ws + OB_Y);
  float*  OHp = (float*)(ws + OB_OHP);
  ushort* Qb  = (ushort*)(ws + OB_Q);
  ushort* Kb  = (ushort*)(ws + OB_K);
  ushort* Vb  = (ushort*)(ws + OB_V);
  float*  Lpt = (float*)(ws + OB_L);
  float*  SQ  = (float*)(ws + OB_SQ);
  float*  G   = (float*)(ws + OB_G);
  float*  SCp = (float*)(ws + OB_SC);
  float* out = (float*)d_out;

  hipMemsetAsync(SQ, 0, 532480, stream);
  k_lnconv<<<dim3(NHW / 64, NB, 3), 256, 0, stream>>>(emb, lnw, lnb, wq, wk, wv, Y);
  k_dw<<<dim3(NH, 12, NB), 256, 0, stream>>>(Y, dwq, dwk, dwv, Qb, Kb, Vb);
  k_gram<<<dim3(NHW / 128, 2, NBH), 256, 0, stream>>>(Qb, Kb, SQ, G);
  k_scale<<<dim3(NBH), 64, 0, stream>>>(SQ, G, SCp);
  k_attn<<<dim3(NHW / 128, NCHK, NBH), 256, 0, stream>>>(Qb, Kb, Vb, SCp, OHp, Lpt);
  k_proj<<<dim3(NHW / 64, NB), 256, 0, stream>>>(OHp, Lpt, pw, pb, emb, out);
}

// Round 4
// 208.360 us; speedup vs baseline: 6.1389x; 1.0693x over previous
//
#include <hip/hip_runtime.h>
#include <hip/hip_bf16.h>
#include <math.h>

#define NB 4
#define NC 64
#define NH 48
#define NW 48
#define NHEADS 4
#define NCH 256
#define NHW 2304
#define NBH 16
#define NCHK 4
#define CHUNK 576

// ws byte offsets. Region [0,18874368) is time-shared:
//   Y (lnconv->dw)  ->  Gp+SQp (gram->scale)  ->  OHp (attn->proj)
#define OB_Y    0ull
#define OB_GP   0ull
#define OB_SQP  4718592ull
#define OB_OHP  0ull
#define OB_Q    18874368ull
#define OB_K    23592960ull
#define OB_V    28311552ull
#define OB_L    33030144ull
#define OB_SC   33619968ull

typedef __bf16 bf16x8 __attribute__((ext_vector_type(8)));
typedef float f32x4 __attribute__((ext_vector_type(4)));
typedef float f32x16 __attribute__((ext_vector_type(16)));

__device__ __forceinline__ float bf2f(ushort u) {
  return __uint_as_float(((unsigned)u) << 16);
}
__device__ __forceinline__ ushort f2bf(float f) {
  __hip_bfloat16 h = __float2bfloat16(f);
  return *(ushort*)&h;
}

// ---------------- fused LayerNorm + 1x1 conv (q/k/v via grid.z), bf16 out ----------------
__global__ __launch_bounds__(256) void k_lnconv(const float* __restrict__ emb,
                                                const float* __restrict__ lw,
                                                const float* __restrict__ lb,
                                                const float* __restrict__ wq,
                                                const float* __restrict__ wk,
                                                const float* __restrict__ wv,
                                                ushort* __restrict__ Y) {
  __shared__ float Xs[64][65];
  __shared__ float mu_s[64], rs_s[64];
  int p0 = blockIdx.x * 64, b = blockIdx.y, qkv = blockIdx.z;
  const float* Wm = qkv == 0 ? wq : (qkv == 1 ? wk : wv);
  const float* src = emb + (size_t)b * NC * NHW + p0;
  for (int e = threadIdx.x; e < 1024; e += 256) {
    int c = e >> 4, p4 = (e & 15) * 4;
    *(float4*)&Xs[c][p4] = *(const float4*)&src[c * NHW + p4];
  }
  __syncthreads();
  if (threadIdx.x < 64) {
    int p = threadIdx.x;
    float s = 0.f, ss = 0.f;
#pragma unroll
    for (int c = 0; c < 64; ++c) { float v = Xs[c][p]; s += v; ss += v * v; }
    float m = s * (1.f / 64.f), v = ss * (1.f / 64.f) - m * m;
    mu_s[p] = m;
    rs_s[p] = rsqrtf(v + 1e-5f);
  }
  __syncthreads();
  int pl = threadIdx.x & 63;
  int og = __builtin_amdgcn_readfirstlane(threadIdx.x >> 6);
  float mu = mu_s[pl], rs = rs_s[pl];
  float xr[64];
#pragma unroll
  for (int c = 0; c < 64; ++c) xr[c] = (Xs[c][pl] - mu) * rs * lw[c] + lb[c];
  ushort* dst = Y + ((size_t)(qkv * NB + b) * NCH + og * 64) * NHW + p0 + pl;
  const float4* W4 = (const float4*)(Wm + og * 64 * 64);
  for (int oi = 0; oi < 64; ++oi) {
    float acc = 0.f;
#pragma unroll
    for (int c4 = 0; c4 < 16; ++c4) {
      float4 w = W4[oi * 16 + c4];
      acc += w.x * xr[c4 * 4] + w.y * xr[c4 * 4 + 1] + w.z * xr[c4 * 4 + 2] + w.w * xr[c4 * 4 + 3];
    }
    dst[(size_t)oi * NHW] = f2bf(acc);
  }
}

// ---------------- depthwise 3x3 (q/k/v merged via grid.y), bf16 in/out ----------------
__global__ __launch_bounds__(256) void k_dw(const ushort* __restrict__ Y,
                                            const float* __restrict__ dwq,
                                            const float* __restrict__ dwk,
                                            const float* __restrict__ dwv,
                                            ushort* __restrict__ Qo,
                                            ushort* __restrict__ Ko,
                                            ushort* __restrict__ Vo) {
  __shared__ ushort Ys[64][3][48];
  __shared__ float Zs[64][49];
  __shared__ float Rs[48];
  int h = blockIdx.x;
  int hd = blockIdx.y & 3, qkv = blockIdx.y >> 2;
  int b = blockIdx.z;
  int bh = b * NHEADS + hd;
  const float* dwp = qkv == 0 ? dwq : (qkv == 1 ? dwk : dwv);
  const ushort* src = Y + ((size_t)(qkv * NB + b) * NCH + hd * 64) * NHW;
  for (int e = threadIdx.x; e < 64 * 3 * 12; e += 256) {
    int c = e / 36, rem = e % 36, r = rem / 12, w4 = (rem % 12) * 4;
    int hh = h + r - 1;
    ushort4 v = (hh >= 0 && hh < NH) ? *(const ushort4*)&src[c * NHW + hh * NW + w4]
                                     : make_ushort4(0, 0, 0, 0);
    *(ushort4*)&Ys[c][r][w4] = v;
  }
  __syncthreads();
  for (int e = threadIdx.x; e < 64 * 48; e += 256) {
    int c = e / 48, w = e % 48;
    const float* kk = dwp + ((size_t)hd * 64 + c) * 9;
    float acc = 0.f;
#pragma unroll
    for (int r = 0; r < 3; ++r)
#pragma unroll
      for (int dx = 0; dx < 3; ++dx) {
        int ww = w + dx - 1;
        float yv = (ww >= 0 && ww < NW) ? bf2f(Ys[c][r][ww]) : 0.f;
        acc += yv * kk[r * 3 + dx];
      }
    Zs[c][w] = acc;
  }
  __syncthreads();
  if (qkv < 2) {
    if (threadIdx.x < 48) {
      int w = threadIdx.x;
      float ss = 0.f;
#pragma unroll
      for (int c = 0; c < 64; ++c) { float z = Zs[c][w]; ss += z * z; }
      Rs[w] = 1.f / fmaxf(sqrtf(ss), 1e-12f);
    }
    __syncthreads();
    ushort* dst = (qkv == 0 ? Qo : Ko) + ((size_t)bh * NHW + h * NW) * 64;
    for (int e = threadIdx.x; e < 48 * 16; e += 256) {
      int w = e >> 4, c4 = (e & 15) * 4;
      float rsc = Rs[w];
      ushort4 u = make_ushort4(f2bf(Zs[c4][w] * rsc), f2bf(Zs[c4 + 1][w] * rsc),
                               f2bf(Zs[c4 + 2][w] * rsc), f2bf(Zs[c4 + 3][w] * rsc));
      *(ushort4*)&dst[w * 64 + c4] = u;
    }
  } else {
    ushort* dst = Vo + (size_t)bh * 64 * NHW + h * NW;
    for (int e = threadIdx.x; e < 64 * 12; e += 256) {
      int c = e / 12, w4 = (e % 12) * 4;
      ushort4 u = make_ushort4(f2bf(Zs[c][w4]), f2bf(Zs[c][w4 + 1]),
                               f2bf(Zs[c][w4 + 2]), f2bf(Zs[c][w4 + 3]));
      *(ushort4*)&dst[(size_t)c * NHW + w4] = u;
    }
  }
}

// ---------------- gram partials via MFMA over LDS-transposed tiles (no atomics) ----------------
// grid (9, 2, 16): 256 rows per block. Gp[ns][qk][bh][64][64] f32, SQp[ns][qk][bh][64].
__global__ __launch_bounds__(256) void k_gram(const ushort* __restrict__ Q,
                                              const ushort* __restrict__ K,
                                              float* __restrict__ Gp,
                                              float* __restrict__ SQp) {
  __shared__ ushort Xt[64][72];   // [c][n] bf16
  int ns = blockIdx.x, qk = blockIdx.y, bh = blockIdx.z;
  const ushort* src = (qk ? K : Q) + ((size_t)bh * NHW + ns * 256) * 64;
  int t = threadIdx.x, lane = t & 63, wv = t >> 6;
  int lr = lane & 15, lg = lane >> 4;
  int ci0 = (wv >> 1) * 32, cj0 = (wv & 1) * 32;
  f32x4 acc[2][2];
#pragma unroll
  for (int i = 0; i < 2; ++i)
#pragma unroll
    for (int j = 0; j < 2; ++j) acc[i][j] = (f32x4){0.f, 0.f, 0.f, 0.f};
  float sq = 0.f;
  for (int it = 0; it < 4; ++it) {
    __syncthreads();
#pragma unroll
    for (int i2 = 0; i2 < 2; ++i2) {
      int n = t & 63, cg = (t >> 6) + 4 * i2;
      union { bf16x8 v; ushort u[8]; } ld;
      ld.v = *(const bf16x8*)&src[(size_t)(it * 64 + n) * 64 + cg * 8];
#pragma unroll
      for (int j = 0; j < 8; ++j) Xt[cg * 8 + j][n] = ld.u[j];
    }
    __syncthreads();
    if (t < 64) {  // column sums (wave 0)
#pragma unroll
      for (int g = 0; g < 8; ++g) {
        union { bf16x8 v; ushort u[8]; } rd;
        rd.v = *(const bf16x8*)&Xt[t][g * 8];
#pragma unroll
        for (int j = 0; j < 8; ++j) sq += bf2f(rd.u[j]);
      }
    }
#pragma unroll
    for (int kh = 0; kh < 2; ++kh) {
      bf16x8 a0 = *(const bf16x8*)&Xt[ci0 + lr][kh * 32 + lg * 8];
      bf16x8 a1 = *(const bf16x8*)&Xt[ci0 + 16 + lr][kh * 32 + lg * 8];
      bf16x8 b0 = *(const bf16x8*)&Xt[cj0 + lr][kh * 32 + lg * 8];
      bf16x8 b1 = *(const bf16x8*)&Xt[cj0 + 16 + lr][kh * 32 + lg * 8];
      acc[0][0] = __builtin_amdgcn_mfma_f32_16x16x32_bf16(a0, b0, acc[0][0], 0, 0, 0);
      acc[0][1] = __builtin_amdgcn_mfma_f32_16x16x32_bf16(a0, b1, acc[0][1], 0, 0, 0);
      acc[1][0] = __builtin_amdgcn_mfma_f32_16x16x32_bf16(a1, b0, acc[1][0], 0, 0, 0);
      acc[1][1] = __builtin_amdgcn_mfma_f32_16x16x32_bf16(a1, b1, acc[1][1], 0, 0, 0);
    }
  }
  float* g = Gp + ((size_t)(ns * 2 + qk) * NBH + bh) * 4096;
#pragma unroll
  for (int ii = 0; ii < 2; ++ii)
#pragma unroll
    for (int jj = 0; jj < 2; ++jj)
#pragma unroll
      for (int r = 0; r < 4; ++r)
        g[(ci0 + ii * 16 + lg * 4 + r) * 64 + cj0 + jj * 16 + lr] = acc[ii][jj][r];
  if (t < 64) SQp[((size_t)(ns * 2 + qk) * NBH + bh) * 64 + t] = sq;
}

// ---------------- reduce partials -> per-(b,h) exp2 scale ----------------
__global__ __launch_bounds__(256) void k_scale(const float* __restrict__ Gp,
                                               const float* __restrict__ SQp,
                                               float* __restrict__ SC) {
  __shared__ float red[256];
  __shared__ float red2[64];
  int bh = blockIdx.x, t = threadIdx.x;
  float ssum = 0.f;
  for (int i = t; i < 4096; i += 256) {
    float gq = 0.f, gk = 0.f;
#pragma unroll
    for (int ns = 0; ns < 9; ++ns) {
      gq += Gp[((size_t)(ns * 2 + 0) * NBH + bh) * 4096 + i];
      gk += Gp[((size_t)(ns * 2 + 1) * NBH + bh) * 4096 + i];
    }
    ssum += gq * gk;
  }
  red[t] = ssum;
  if (t < 64) {
    float sq_q = 0.f, sq_k = 0.f;
#pragma unroll
    for (int ns = 0; ns < 9; ++ns) {
      sq_q += SQp[((size_t)(ns * 2 + 0) * NBH + bh) * 64 + t];
      sq_k += SQp[((size_t)(ns * 2 + 1) * NBH + bh) * 64 + t];
    }
    red2[t] = sq_q * sq_k;
  }
  __syncthreads();
  if (t == 0) {
    double S = 0.0, A = 0.0;
    for (int i = 0; i < 256; ++i) S += red[i];
    for (int i = 0; i < 64; ++i) A += red2[i];
    const double N2 = (double)NHW * (double)NHW;
    double mean = A / (N2 * 48.0);
    double ea2 = S / (N2 * 2304.0);
    double var = ea2 - mean * mean;
    SC[bh] = (float)((1.0 / sqrt(var + 1e-5)) / 48.0 * 1.4426950408889634);
  }
}

// ---------------- flash attention v4: 32x32 MFMA, no LDS, no barriers ----------------
// grid (18, 4, 16), 4 waves/block, each wave independent: 32 q-rows x 576-m chunk.
// Swapped QK^T: D rows = m = (reg&3)+8*(reg>>2)+4h, cols = q = lane&31.
// PV A-frag assembled register-locally with 4 v_permlane32_swap_b32.
__global__ __launch_bounds__(256) void k_attn(const ushort* __restrict__ Q,
                                              const ushort* __restrict__ K,
                                              const ushort* __restrict__ V,
                                              const float* __restrict__ SC,
                                              ushort* __restrict__ OHp,
                                              float* __restrict__ Lp) {
  int qt = blockIdx.x, chunk = blockIdx.y, bh = blockIdx.z;
  int t = threadIdx.x, lane = t & 63, wv = t >> 6;
  int ql = lane & 31, h = lane >> 5;
  int q0 = qt * 128 + wv * 32;
  size_t basen = (size_t)bh * NHW;
  float sc2 = SC[bh];
  const ushort* qp = Q + (basen + q0 + ql) * 64 + h * 8;
  bf16x8 qfr[4];
#pragma unroll
  for (int kc = 0; kc < 4; ++kc) qfr[kc] = *(const bf16x8*)(qp + kc * 16);
  f32x16 o0 = {}, o1 = {};
  float lp = 0.f;
  const ushort* kbase = K + (basen + chunk * CHUNK + ql) * 64 + h * 8;
  const ushort* vbase = V + ((size_t)bh * 64 + ql) * NHW + chunk * CHUNK + h * 8;
  for (int mt = 0; mt < CHUNK / 32; ++mt) {
    const ushort* kp = kbase + mt * 32 * 64;
    bf16x8 ka0 = *(const bf16x8*)(kp);
    bf16x8 ka1 = *(const bf16x8*)(kp + 16);
    bf16x8 ka2 = *(const bf16x8*)(kp + 32);
    bf16x8 ka3 = *(const bf16x8*)(kp + 48);
    f32x16 s = {};
    s = __builtin_amdgcn_mfma_f32_32x32x16_bf16(ka0, qfr[0], s, 0, 0, 0);
    s = __builtin_amdgcn_mfma_f32_32x32x16_bf16(ka1, qfr[1], s, 0, 0, 0);
    s = __builtin_amdgcn_mfma_f32_32x32x16_bf16(ka2, qfr[2], s, 0, 0, 0);
    s = __builtin_amdgcn_mfma_f32_32x32x16_bf16(ka3, qfr[3], s, 0, 0, 0);
    float p[16];
#pragma unroll
    for (int r = 0; r < 16; ++r) {
      p[r] = __builtin_exp2f(s[r] * sc2);
      lp += p[r];
    }
    uint u[8];
#pragma unroll
    for (int i = 0; i < 8; ++i)
      u[i] = (__float_as_uint(p[2 * i + 1]) & 0xffff0000u) | (__float_as_uint(p[2 * i]) >> 16);
    asm volatile("v_permlane32_swap_b32 %0, %1" : "+v"(u[0]), "+v"(u[2]));
    asm volatile("v_permlane32_swap_b32 %0, %1" : "+v"(u[1]), "+v"(u[3]));
    asm volatile("v_permlane32_swap_b32 %0, %1" : "+v"(u[4]), "+v"(u[6]));
    asm volatile("v_permlane32_swap_b32 %0, %1" : "+v"(u[5]), "+v"(u[7]));
    union { uint uu[4]; bf16x8 v; } pa0, pa1;
    pa0.uu[0] = u[0]; pa0.uu[1] = u[1]; pa0.uu[2] = u[2]; pa0.uu[3] = u[3];
    pa1.uu[0] = u[4]; pa1.uu[1] = u[5]; pa1.uu[2] = u[6]; pa1.uu[3] = u[7];
    const ushort* vp = vbase + mt * 32;
    bf16x8 vb00 = *(const bf16x8*)(vp);
    bf16x8 vb01 = *(const bf16x8*)(vp + 16);
    bf16x8 vb10 = *(const bf16x8*)(vp + (size_t)32 * NHW);
    bf16x8 vb11 = *(const bf16x8*)(vp + (size_t)32 * NHW + 16);
    o0 = __builtin_amdgcn_mfma_f32_32x32x16_bf16(pa0.v, vb00, o0, 0, 0, 0);
    o0 = __builtin_amdgcn_mfma_f32_32x32x16_bf16(pa1.v, vb01, o0, 0, 0, 0);
    o1 = __builtin_amdgcn_mfma_f32_32x32x16_bf16(pa0.v, vb10, o1, 0, 0, 0);
    o1 = __builtin_amdgcn_mfma_f32_32x32x16_bf16(pa1.v, vb11, o1, 0, 0, 0);
  }
  lp += __shfl_xor(lp, 32);
  lp *= 0.99609375f;  // compensate bf16 truncation mean bias of P
  if (h == 0) Lp[(size_t)(chunk * NBH + bh) * NHW + q0 + ql] = lp;
  ushort* od = OHp + ((size_t)(chunk * NBH + bh) * NHW + q0) * 64;
#pragma unroll
  for (int r = 0; r < 16; ++r) {
    int qrow = (r & 3) + 8 * (r >> 2) + 4 * h;
    od[(size_t)qrow * 64 + ql] = f2bf(o0[r]);
    od[(size_t)qrow * 64 + 32 + ql] = f2bf(o1[r]);
  }
}

// ---------------- combine partials + head-mean + projection + residual ----------------
__global__ __launch_bounds__(256) void k_proj(const ushort* __restrict__ OHp,
                                              const float* __restrict__ Lp,
                                              const float* __restrict__ PW,
                                              const float* __restrict__ PB,
                                              const float* __restrict__ org,
                                              float* __restrict__ out) {
  __shared__ float Ls[4][4][16];
  __shared__ float linv[4][16];
  __shared__ float Ms[64][17];
  int p0 = blockIdx.x * 16, b = blockIdx.y;
  int t = threadIdx.x;
  {
    int ck = t >> 6, hd = (t >> 4) & 3, p = t & 15;
    Ls[ck][hd][p] = Lp[(size_t)(ck * NBH + b * 4 + hd) * NHW + p0 + p];
  }
  __syncthreads();
  if (t < 64) {
    int hd = t >> 4, p = t & 15;
    linv[hd][p] = 1.f / (Ls[0][hd][p] + Ls[1][hd][p] + Ls[2][hd][p] + Ls[3][hd][p]);
  }
  __syncthreads();
  {
    int p = t >> 4, c4 = (t & 15) * 4;
    float a0 = 0.f, a1 = 0.f, a2 = 0.f, a3 = 0.f;
#pragma unroll
    for (int hd = 0; hd < 4; ++hd) {
      float s0 = 0.f, s1 = 0.f, s2 = 0.f, s3 = 0.f;
#pragma unroll
      for (int ck = 0; ck < 4; ++ck) {
        ushort4 u = *(const ushort4*)&OHp[((size_t)(ck * NBH + b * 4 + hd) * NHW + p0 + p) * 64 + c4];
        s0 += bf2f(u.x); s1 += bf2f(u.y); s2 += bf2f(u.z); s3 += bf2f(u.w);
      }
      float li = linv[hd][p];
      a0 += s0 * li; a1 += s1 * li; a2 += s2 * li; a3 += s3 * li;
    }
    Ms[c4][p] = 0.25f * a0;
    Ms[c4 + 1][p] = 0.25f * a1;
    Ms[c4 + 2][p] = 0.25f * a2;
    Ms[c4 + 3][p] = 0.25f * a3;
  }
  __syncthreads();
  int p = t & 15, og = t >> 4;
  float acc[4];
#pragma unroll
  for (int i = 0; i < 4; ++i) acc[i] = PB[og * 4 + i];
  for (int c = 0; c < 64; ++c) {
    float xr = Ms[c][p];
#pragma unroll
    for (int i = 0; i < 4; ++i) acc[i] += PW[(og * 4 + i) * 64 + c] * xr;
  }
  const float* orgp = org + (size_t)b * NC * NHW + p0 + p;
  float* outp = out + (size_t)b * NC * NHW + p0 + p;
#pragma unroll
  for (int i = 0; i < 4; ++i) {
    int oc = og * 4 + i;
    outp[(size_t)oc * NHW] = orgp[(size_t)oc * NHW] + acc[i];
  }
}

extern "C" void kernel_launch(void* const* d_in, const int* in_sizes, int n_in,
                              void* d_out, int out_size, void* d_ws, size_t ws_size,
                              hipStream_t stream) {
  const float* emb = (const float*)d_in[0];
  const float* lnw = (const float*)d_in[1];
  const float* lnb = (const float*)d_in[2];
  const float* wq  = (const float*)d_in[3];
  const float* wk  = (const float*)d_in[4];
  const float* wv  = (const float*)d_in[5];
  const float* dwq = (const float*)d_in[6];
  const float* dwk = (const float*)d_in[7];
  const float* dwv = (const float*)d_in[8];
  const float* pw  = (const float*)d_in[9];
  const float* pb  = (const float*)d_in[10];
  char* ws = (char*)d_ws;
  ushort* Y   = (ushort*)(ws + OB_Y);
  float*  Gp  = (float*)(ws + OB_GP);
  float*  SQp = (float*)(ws + OB_SQP);
  ushort* OHp = (ushort*)(ws + OB_OHP);
  ushort* Qb  = (ushort*)(ws + OB_Q);
  ushort* Kb  = (ushort*)(ws + OB_K);
  ushort* Vb  = (ushort*)(ws + OB_V);
  float*  Lpt = (float*)(ws + OB_L);
  float*  SCp = (float*)(ws + OB_SC);
  float* out = (float*)d_out;

  k_lnconv<<<dim3(NHW / 64, NB, 3), 256, 0, stream>>>(emb, lnw, lnb, wq, wk, wv, Y);
  k_dw<<<dim3(NH, 12, NB), 256, 0, stream>>>(Y, dwq, dwk, dwv, Qb, Kb, Vb);
  k_gram<<<dim3(9, 2, NBH), 256, 0, stream>>>(Qb, Kb, Gp, SQp);
  k_scale<<<dim3(NBH), 256, 0, stream>>>(Gp, SQp, SCp);
  k_attn<<<dim3(18, NCHK, NBH), 256, 0, stream>>>(Qb, Kb, Vb, SCp, OHp, Lpt);
  k_proj<<<dim3(NHW / 16, NB), 256, 0, stream>>>(OHp, Lpt, pw, pb, emb, out);
}

// Round 6
// 171.500 us; speedup vs baseline: 7.4584x; 1.2149x over previous
//
#include <hip/hip_runtime.h>
#include <hip/hip_bf16.h>
#include <math.h>

#define NB 4
#define NC 64
#define NH 48
#define NW 48
#define NHEADS 4
#define NCH 256
#define NHW 2304
#define NBH 16
#define NCHK 4
#define CHUNK 576
#define NT (CHUNK / 32)

// ws byte offsets. Region [0,18874368) is time-shared:
//   Y (lnconv->dw)  ->  Gp+SQp (gram->scale)  ->  OHp (attn->proj)
#define OB_Y    0ull
#define OB_GP   0ull
#define OB_SQP  4718592ull
#define OB_OHP  0ull
#define OB_Q    18874368ull
#define OB_K    23592960ull
#define OB_V    28311552ull
#define OB_L    33030144ull
#define OB_SC   33619968ull

typedef __bf16 bf16x8 __attribute__((ext_vector_type(8)));
typedef float f32x4 __attribute__((ext_vector_type(4)));
typedef float f32x16 __attribute__((ext_vector_type(16)));

__device__ __forceinline__ float bf2f(ushort u) {
  return __uint_as_float(((unsigned)u) << 16);
}
__device__ __forceinline__ ushort f2bf(float f) {
  __hip_bfloat16 h = __float2bfloat16(f);
  return *(ushort*)&h;
}
__device__ __forceinline__ void gload16(const void* g, void* l) {
  __builtin_amdgcn_global_load_lds((const __attribute__((address_space(1))) unsigned int*)g,
                                   (__attribute__((address_space(3))) unsigned int*)l, 16, 0, 0);
}

// ---------------- fused LayerNorm + 1x1 conv (q/k/v via grid.z), bf16 out ----------------
__global__ __launch_bounds__(256) void k_lnconv(const float* __restrict__ emb,
                                                const float* __restrict__ lw,
                                                const float* __restrict__ lb,
                                                const float* __restrict__ wq,
                                                const float* __restrict__ wk,
                                                const float* __restrict__ wv,
                                                ushort* __restrict__ Y) {
  __shared__ float Xs[64][65];
  __shared__ float mu_s[64], rs_s[64];
  int p0 = blockIdx.x * 64, b = blockIdx.y, qkv = blockIdx.z;
  const float* Wm = qkv == 0 ? wq : (qkv == 1 ? wk : wv);
  const float* src = emb + (size_t)b * NC * NHW + p0;
  for (int e = threadIdx.x; e < 1024; e += 256) {
    int c = e >> 4, p4 = (e & 15) * 4;
    *(float4*)&Xs[c][p4] = *(const float4*)&src[c * NHW + p4];
  }
  __syncthreads();
  if (threadIdx.x < 64) {
    int p = threadIdx.x;
    float s = 0.f, ss = 0.f;
#pragma unroll
    for (int c = 0; c < 64; ++c) { float v = Xs[c][p]; s += v; ss += v * v; }
    float m = s * (1.f / 64.f), v = ss * (1.f / 64.f) - m * m;
    mu_s[p] = m;
    rs_s[p] = rsqrtf(v + 1e-5f);
  }
  __syncthreads();
  int pl = threadIdx.x & 63;
  int og = __builtin_amdgcn_readfirstlane(threadIdx.x >> 6);
  float mu = mu_s[pl], rs = rs_s[pl];
  float xr[64];
#pragma unroll
  for (int c = 0; c < 64; ++c) xr[c] = (Xs[c][pl] - mu) * rs * lw[c] + lb[c];
  ushort* dst = Y + ((size_t)(qkv * NB + b) * NCH + og * 64) * NHW + p0 + pl;
  const float4* W4 = (const float4*)(Wm + og * 64 * 64);
  for (int oi = 0; oi < 64; ++oi) {
    float acc = 0.f;
#pragma unroll
    for (int c4 = 0; c4 < 16; ++c4) {
      float4 w = W4[oi * 16 + c4];
      acc += w.x * xr[c4 * 4] + w.y * xr[c4 * 4 + 1] + w.z * xr[c4 * 4 + 2] + w.w * xr[c4 * 4 + 3];
    }
    dst[(size_t)oi * NHW] = f2bf(acc);
  }
}

// ---------------- depthwise 3x3 (q/k/v merged via grid.y), bf16 in/out ----------------
// Q/K out layout: [bh][cg=c>>3][n][8]   (attn-native, coalesced)
// V   out layout: [bh][mb=n>>3][c][8]
__global__ __launch_bounds__(256) void k_dw(const ushort* __restrict__ Y,
                                            const float* __restrict__ dwq,
                                            const float* __restrict__ dwk,
                                            const float* __restrict__ dwv,
                                            ushort* __restrict__ Qo,
                                            ushort* __restrict__ Ko,
                                            ushort* __restrict__ Vo) {
  __shared__ ushort Ys[64][3][48];
  __shared__ float Zs[64][49];
  __shared__ float Rs[48];
  int h = blockIdx.x;
  int hd = blockIdx.y & 3, qkv = blockIdx.y >> 2;
  int b = blockIdx.z;
  int bh = b * NHEADS + hd;
  const float* dwp = qkv == 0 ? dwq : (qkv == 1 ? dwk : dwv);
  const ushort* src = Y + ((size_t)(qkv * NB + b) * NCH + hd * 64) * NHW;
  for (int e = threadIdx.x; e < 64 * 3 * 12; e += 256) {
    int c = e / 36, rem = e % 36, r = rem / 12, w4 = (rem % 12) * 4;
    int hh = h + r - 1;
    ushort4 v = (hh >= 0 && hh < NH) ? *(const ushort4*)&src[c * NHW + hh * NW + w4]
                                     : make_ushort4(0, 0, 0, 0);
    *(ushort4*)&Ys[c][r][w4] = v;
  }
  __syncthreads();
  for (int e = threadIdx.x; e < 64 * 48; e += 256) {
    int c = e / 48, w = e % 48;
    const float* kk = dwp + ((size_t)hd * 64 + c) * 9;
    float acc = 0.f;
#pragma unroll
    for (int r = 0; r < 3; ++r)
#pragma unroll
      for (int dx = 0; dx < 3; ++dx) {
        int ww = w + dx - 1;
        float yv = (ww >= 0 && ww < NW) ? bf2f(Ys[c][r][ww]) : 0.f;
        acc += yv * kk[r * 3 + dx];
      }
    Zs[c][w] = acc;
  }
  __syncthreads();
  if (qkv < 2) {
    if (threadIdx.x < 48) {
      int w = threadIdx.x;
      float ss = 0.f;
#pragma unroll
      for (int c = 0; c < 64; ++c) { float z = Zs[c][w]; ss += z * z; }
      Rs[w] = 1.f / fmaxf(sqrtf(ss), 1e-12f);
    }
    __syncthreads();
    ushort* dst = (qkv == 0 ? Qo : Ko) + (size_t)bh * NHW * 64;
    for (int e = threadIdx.x; e < 48 * 16; e += 256) {
      int w = e >> 4, c4 = (e & 15) * 4;
      float rsc = Rs[w];
      ushort4 u = make_ushort4(f2bf(Zs[c4][w] * rsc), f2bf(Zs[c4 + 1][w] * rsc),
                               f2bf(Zs[c4 + 2][w] * rsc), f2bf(Zs[c4 + 3][w] * rsc));
      *(ushort4*)&dst[((size_t)(c4 >> 3) * NHW + h * NW + w) * 8 + (c4 & 7)] = u;
    }
  } else {
    ushort* dst = Vo + (size_t)bh * NHW * 64;
    for (int e = threadIdx.x; e < 64 * 12; e += 256) {
      int c = e / 12, w4 = (e % 12) * 4;
      ushort4 u = make_ushort4(f2bf(Zs[c][w4]), f2bf(Zs[c][w4 + 1]),
                               f2bf(Zs[c][w4 + 2]), f2bf(Zs[c][w4 + 3]));
      *(ushort4*)&dst[((size_t)(h * 6 + (w4 >> 3)) * 64 + c) * 8 + (w4 & 7)] = u;
    }
  }
}

// ---------------- gram partials via MFMA over LDS-transposed tiles ----------------
// grid (9, 2, 16). Gp[ns][qk][bh][64][64] f32, SQp[ns][qk][bh][64].
__global__ __launch_bounds__(256) void k_gram(const ushort* __restrict__ Q,
                                              const ushort* __restrict__ K,
                                              float* __restrict__ Gp,
                                              float* __restrict__ SQp) {
  __shared__ ushort Xt[64][72];   // [c][n] bf16
  int ns = blockIdx.x, qk = blockIdx.y, bh = blockIdx.z;
  const ushort* src = (qk ? K : Q) + (size_t)bh * NHW * 64;
  int t = threadIdx.x, lane = t & 63, wv = t >> 6;
  int lr = lane & 15, lg = lane >> 4;
  int ci0 = (wv >> 1) * 32, cj0 = (wv & 1) * 32;
  f32x4 acc[2][2];
#pragma unroll
  for (int i = 0; i < 2; ++i)
#pragma unroll
    for (int j = 0; j < 2; ++j) acc[i][j] = (f32x4){0.f, 0.f, 0.f, 0.f};
  float sq = 0.f;
  for (int it = 0; it < 4; ++it) {
    __syncthreads();
#pragma unroll
    for (int i2 = 0; i2 < 2; ++i2) {
      int n = t & 63, cg = (t >> 6) + 4 * i2;
      union { bf16x8 v; ushort u[8]; } ld;
      ld.v = *(const bf16x8*)&src[((size_t)cg * NHW + ns * 256 + it * 64 + n) * 8];
#pragma unroll
      for (int j = 0; j < 8; ++j) Xt[cg * 8 + j][n] = ld.u[j];
    }
    __syncthreads();
    if (t < 64) {  // column sums (wave 0)
#pragma unroll
      for (int g = 0; g < 8; ++g) {
        union { bf16x8 v; ushort u[8]; } rd;
        rd.v = *(const bf16x8*)&Xt[t][g * 8];
#pragma unroll
        for (int j = 0; j < 8; ++j) sq += bf2f(rd.u[j]);
      }
    }
#pragma unroll
    for (int kh = 0; kh < 2; ++kh) {
      bf16x8 a0 = *(const bf16x8*)&Xt[ci0 + lr][kh * 32 + lg * 8];
      bf16x8 a1 = *(const bf16x8*)&Xt[ci0 + 16 + lr][kh * 32 + lg * 8];
      bf16x8 b0 = *(const bf16x8*)&Xt[cj0 + lr][kh * 32 + lg * 8];
      bf16x8 b1 = *(const bf16x8*)&Xt[cj0 + 16 + lr][kh * 32 + lg * 8];
      acc[0][0] = __builtin_amdgcn_mfma_f32_16x16x32_bf16(a0, b0, acc[0][0], 0, 0, 0);
      acc[0][1] = __builtin_amdgcn_mfma_f32_16x16x32_bf16(a0, b1, acc[0][1], 0, 0, 0);
      acc[1][0] = __builtin_amdgcn_mfma_f32_16x16x32_bf16(a1, b0, acc[1][0], 0, 0, 0);
      acc[1][1] = __builtin_amdgcn_mfma_f32_16x16x32_bf16(a1, b1, acc[1][1], 0, 0, 0);
    }
  }
  float* g = Gp + ((size_t)(ns * 2 + qk) * NBH + bh) * 4096;
#pragma unroll
  for (int ii = 0; ii < 2; ++ii)
#pragma unroll
    for (int jj = 0; jj < 2; ++jj)
#pragma unroll
      for (int r = 0; r < 4; ++r)
        g[(ci0 + ii * 16 + lg * 4 + r) * 64 + cj0 + jj * 16 + lr] = acc[ii][jj][r];
  if (t < 64) SQp[((size_t)(ns * 2 + qk) * NBH + bh) * 64 + t] = sq;
}

// ---------------- reduce partials -> per-(b,h) exp2 scale ----------------
__global__ __launch_bounds__(256) void k_scale(const float* __restrict__ Gp,
                                               const float* __restrict__ SQp,
                                               float* __restrict__ SC) {
  __shared__ float red[256];
  __shared__ float red2[64];
  int bh = blockIdx.x, t = threadIdx.x;
  float ssum = 0.f;
  for (int i = t; i < 4096; i += 256) {
    float gq = 0.f, gk = 0.f;
#pragma unroll
    for (int ns = 0; ns < 9; ++ns) {
      gq += Gp[((size_t)(ns * 2 + 0) * NBH + bh) * 4096 + i];
      gk += Gp[((size_t)(ns * 2 + 1) * NBH + bh) * 4096 + i];
    }
    ssum += gq * gk;
  }
  red[t] = ssum;
  if (t < 64) {
    float sq_q = 0.f, sq_k = 0.f;
#pragma unroll
    for (int ns = 0; ns < 9; ++ns) {
      sq_q += SQp[((size_t)(ns * 2 + 0) * NBH + bh) * 64 + t];
      sq_k += SQp[((size_t)(ns * 2 + 1) * NBH + bh) * 64 + t];
    }
    red2[t] = sq_q * sq_k;
  }
  __syncthreads();
  if (t == 0) {
    double S = 0.0, A = 0.0;
    for (int i = 0; i < 256; ++i) S += red[i];
    for (int i = 0; i < 64; ++i) A += red2[i];
    const double N2 = (double)NHW * (double)NHW;
    double mean = A / (N2 * 48.0);
    double ea2 = S / (N2 * 2304.0);
    double var = ea2 - mean * mean;
    SC[bh] = (float)((1.0 / sqrt(var + 1e-5)) / 48.0 * 1.4426950408889634);
  }
}

// ---------------- flash attention v5b: 32x32 MFMA, LDS-staged double-buffer ----------------
// grid (9, 4, 16), 4 waves/block; wave owns 64 q-rows (2 q-blocks of 32) x 576-m chunk.
// K LDS: [cg][32 m][8]  (cg-stride = 256 ushorts); V LDS: [mg][64 c][8] (mg-stride = 512).
// 2-phase pipeline: STAGE(next) ; compute(cur) ; barrier.
__global__ __launch_bounds__(256, 2) void k_attn(const ushort* __restrict__ Q,
                                                 const ushort* __restrict__ K,
                                                 const ushort* __restrict__ V,
                                                 const float* __restrict__ SC,
                                                 ushort* __restrict__ OHp,
                                                 float* __restrict__ Lp) {
  __shared__ ushort Kl[2][2048];
  __shared__ ushort Vl[2][2048];
  int qt = blockIdx.x, chunk = blockIdx.y, bh = blockIdx.z;
  int t = threadIdx.x, lane = t & 63, wv = t >> 6;
  int ql = lane & 31, h = lane >> 5;
  int q0 = qt * 256 + wv * 64;
  int m00 = chunk * CHUNK;
  const ushort* base = Q + (size_t)bh * NHW * 64;   // same stride for K/V bases
  float sc2 = SC[bh];

  // Q fragments: 2 q-blocks x 4 k-chunks
  bf16x8 qfr[2][4];
#pragma unroll
  for (int qb = 0; qb < 2; ++qb)
#pragma unroll
    for (int kc = 0; kc < 4; ++kc)
      qfr[qb][kc] = *(const bf16x8*)&base[((size_t)(kc * 2 + h) * NHW + q0 + qb * 32 + ql) * 8];

  // staging source pointers (per-lane)
  const ushort* kst = K + (size_t)bh * NHW * 64 + ((size_t)(wv * 2 + h) * NHW + m00 + ql) * 8;
  const ushort* vst = V + (size_t)bh * NHW * 64 + ((size_t)((m00 >> 3) + wv) * 64 + lane) * 8;

  f32x16 o[2][2];
#pragma unroll
  for (int qb = 0; qb < 2; ++qb) { o[qb][0] = (f32x16){}; o[qb][1] = (f32x16){}; }
  float lp[2] = {0.f, 0.f};

  // prologue: stage tile 0
  gload16(kst, (void*)&Kl[0][wv * 512]);
  gload16(vst, (void*)&Vl[0][wv * 512]);
  __syncthreads();

  int cur = 0;
  for (int mt = 0; mt < NT; ++mt) {
    if (mt + 1 < NT) {
      gload16(kst + (mt + 1) * 256, (void*)&Kl[cur ^ 1][wv * 512]);
      gload16(vst + (mt + 1) * 2048, (void*)&Vl[cur ^ 1][wv * 512]);
    }
    bf16x8 ka[4], vb[4];
#pragma unroll
    for (int i = 0; i < 4; ++i)
      ka[i] = *(const bf16x8*)&Kl[cur][(2 * i + h) * 256 + ql * 8];
    vb[0] = *(const bf16x8*)&Vl[cur][h * 512 + ql * 8];
    vb[1] = *(const bf16x8*)&Vl[cur][(2 + h) * 512 + ql * 8];
    vb[2] = *(const bf16x8*)&Vl[cur][h * 512 + (ql + 32) * 8];
    vb[3] = *(const bf16x8*)&Vl[cur][(2 + h) * 512 + (ql + 32) * 8];
#pragma unroll
    for (int qb = 0; qb < 2; ++qb) {
      f32x16 s = {};
      s = __builtin_amdgcn_mfma_f32_32x32x16_bf16(ka[0], qfr[qb][0], s, 0, 0, 0);
      s = __builtin_amdgcn_mfma_f32_32x32x16_bf16(ka[1], qfr[qb][1], s, 0, 0, 0);
      s = __builtin_amdgcn_mfma_f32_32x32x16_bf16(ka[2], qfr[qb][2], s, 0, 0, 0);
      s = __builtin_amdgcn_mfma_f32_32x32x16_bf16(ka[3], qfr[qb][3], s, 0, 0, 0);
      float p[16];
#pragma unroll
      for (int r = 0; r < 16; ++r) {
        p[r] = __builtin_exp2f(s[r] * sc2);
        lp[qb] += p[r];
      }
      uint u[8];
#pragma unroll
      for (int i = 0; i < 8; ++i)
        u[i] = (__float_as_uint(p[2 * i + 1]) & 0xffff0000u) | (__float_as_uint(p[2 * i]) >> 16);
      asm volatile("v_permlane32_swap_b32 %0, %1" : "+v"(u[0]), "+v"(u[2]));
      asm volatile("v_permlane32_swap_b32 %0, %1" : "+v"(u[1]), "+v"(u[3]));
      asm volatile("v_permlane32_swap_b32 %0, %1" : "+v"(u[4]), "+v"(u[6]));
      asm volatile("v_permlane32_swap_b32 %0, %1" : "+v"(u[5]), "+v"(u[7]));
      union { uint uu[4]; bf16x8 v; } pa0, pa1;
      pa0.uu[0] = u[0]; pa0.uu[1] = u[1]; pa0.uu[2] = u[2]; pa0.uu[3] = u[3];
      pa1.uu[0] = u[4]; pa1.uu[1] = u[5]; pa1.uu[2] = u[6]; pa1.uu[3] = u[7];
      o[qb][0] = __builtin_amdgcn_mfma_f32_32x32x16_bf16(pa0.v, vb[0], o[qb][0], 0, 0, 0);
      o[qb][0] = __builtin_amdgcn_mfma_f32_32x32x16_bf16(pa1.v, vb[1], o[qb][0], 0, 0, 0);
      o[qb][1] = __builtin_amdgcn_mfma_f32_32x32x16_bf16(pa0.v, vb[2], o[qb][1], 0, 0, 0);
      o[qb][1] = __builtin_amdgcn_mfma_f32_32x32x16_bf16(pa1.v, vb[3], o[qb][1], 0, 0, 0);
    }
    __syncthreads();
    cur ^= 1;
  }

#pragma unroll
  for (int qb = 0; qb < 2; ++qb) {
    lp[qb] += __shfl_xor(lp[qb], 32);
    lp[qb] *= 0.99609375f;  // compensate bf16 truncation mean bias of P
  }
  if (h == 0) {
#pragma unroll
    for (int qb = 0; qb < 2; ++qb)
      Lp[(size_t)(chunk * NBH + bh) * NHW + q0 + qb * 32 + ql] = lp[qb];
  }
  ushort* od = OHp + ((size_t)(chunk * NBH + bh) * NHW + q0) * 64;
#pragma unroll
  for (int qb = 0; qb < 2; ++qb)
#pragma unroll
    for (int r = 0; r < 16; ++r) {
      int qrow = qb * 32 + (r & 3) + 8 * (r >> 2) + 4 * h;
      od[(size_t)qrow * 64 + ql] = f2bf(o[qb][0][r]);
      od[(size_t)qrow * 64 + 32 + ql] = f2bf(o[qb][1][r]);
    }
}

// ---------------- combine partials + head-mean + projection + residual ----------------
__global__ __launch_bounds__(256) void k_proj(const ushort* __restrict__ OHp,
                                              const float* __restrict__ Lp,
                                              const float* __restrict__ PW,
                                              const float* __restrict__ PB,
                                              const float* __restrict__ org,
                                              float* __restrict__ out) {
  __shared__ float Ls[4][4][16];
  __shared__ float linv[4][16];
  __shared__ float Ms[64][17];
  int p0 = blockIdx.x * 16, b = blockIdx.y;
  int t = threadIdx.x;
  {
    int ck = t >> 6, hd = (t >> 4) & 3, p = t & 15;
    Ls[ck][hd][p] = Lp[(size_t)(ck * NBH + b * 4 + hd) * NHW + p0 + p];
  }
  __syncthreads();
  if (t < 64) {
    int hd = t >> 4, p = t & 15;
    linv[hd][p] = 1.f / (Ls[0][hd][p] + Ls[1][hd][p] + Ls[2][hd][p] + Ls[3][hd][p]);
  }
  __syncthreads();
  {
    int p = t >> 4, c4 = (t & 15) * 4;
    float a0 = 0.f, a1 = 0.f, a2 = 0.f, a3 = 0.f;
#pragma unroll
    for (int hd = 0; hd < 4; ++hd) {
      float s0 = 0.f, s1 = 0.f, s2 = 0.f, s3 = 0.f;
#pragma unroll
      for (int ck = 0; ck < 4; ++ck) {
        ushort4 u = *(const ushort4*)&OHp[((size_t)(ck * NBH + b * 4 + hd) * NHW + p0 + p) * 64 + c4];
        s0 += bf2f(u.x); s1 += bf2f(u.y); s2 += bf2f(u.z); s3 += bf2f(u.w);
      }
      float li = linv[hd][p];
      a0 += s0 * li; a1 += s1 * li; a2 += s2 * li; a3 += s3 * li;
    }
    Ms[c4][p] = 0.25f * a0;
    Ms[c4 + 1][p] = 0.25f * a1;
    Ms[c4 + 2][p] = 0.25f * a2;
    Ms[c4 + 3][p] = 0.25f * a3;
  }
  __syncthreads();
  int p = t & 15, og = t >> 4;
  float acc[4];
#pragma unroll
  for (int i = 0; i < 4; ++i) acc[i] = PB[og * 4 + i];
  for (int c = 0; c < 64; ++c) {
    float xr = Ms[c][p];
#pragma unroll
    for (int i = 0; i < 4; ++i) acc[i] += PW[(og * 4 + i) * 64 + c] * xr;
  }
  const float* orgp = org + (size_t)b * NC * NHW + p0 + p;
  float* outp = out + (size_t)b * NC * NHW + p0 + p;
#pragma unroll
  for (int i = 0; i < 4; ++i) {
    int oc = og * 4 + i;
    outp[(size_t)oc * NHW] = orgp[(size_t)oc * NHW] + acc[i];
  }
}

extern "C" void kernel_launch(void* const* d_in, const int* in_sizes, int n_in,
                              void* d_out, int out_size, void* d_ws, size_t ws_size,
                              hipStream_t stream) {
  const float* emb = (const float*)d_in[0];
  const float* lnw = (const float*)d_in[1];
  const float* lnb = (const float*)d_in[2];
  const float* wq  = (const float*)d_in[3];
  const float* wk  = (const float*)d_in[4];
  const float* wv  = (const float*)d_in[5];
  const float* dwq = (const float*)d_in[6];
  const float* dwk = (const float*)d_in[7];
  const float* dwv = (const float*)d_in[8];
  const float* pw  = (const float*)d_in[9];
  const float* pb  = (const float*)d_in[10];
  char* ws = (char*)d_ws;
  ushort* Y   = (ushort*)(ws + OB_Y);
  float*  Gp  = (float*)(ws + OB_GP);
  float*  SQp = (float*)(ws + OB_SQP);
  ushort* OHp = (ushort*)(ws + OB_OHP);
  ushort* Qb  = (ushort*)(ws + OB_Q);
  ushort* Kb  = (ushort*)(ws + OB_K);
  ushort* Vb  = (ushort*)(ws + OB_V);
  float*  Lpt = (float*)(ws + OB_L);
  float*  SCp = (float*)(ws + OB_SC);
  float* out = (float*)d_out;

  k_lnconv<<<dim3(NHW / 64, NB, 3), 256, 0, stream>>>(emb, lnw, lnb, wq, wk, wv, Y);
  k_dw<<<dim3(NH, 12, NB), 256, 0, stream>>>(Y, dwq, dwk, dwv, Qb, Kb, Vb);
  k_gram<<<dim3(9, 2, NBH), 256, 0, stream>>>(Qb, Kb, Gp, SQp);
  k_scale<<<dim3(NBH), 256, 0, stream>>>(Gp, SQp, SCp);
  k_attn<<<dim3(9, NCHK, NBH), 256, 0, stream>>>(Qb, Kb, Vb, SCp, OHp, Lpt);
  k_proj<<<dim3(NHW / 16, NB), 256, 0, stream>>>(OHp, Lpt, pw, pb, emb, out);
}

// Round 7
// 125.875 us; speedup vs baseline: 10.1618x; 1.3625x over previous
//
#include <hip/hip_runtime.h>
#include <hip/hip_bf16.h>
#include <math.h>

#define NB 4
#define NC 64
#define NH 48
#define NW 48
#define NHEADS 4
#define NCH 256
#define NHW 2304
#define NBH 16
#define NCHK 4
#define CHUNK 576
#define NT (CHUNK / 32)

// ws byte offsets. Region [0,18874368) is time-shared:
//   Y (lnconv->dw)  ->  Gp+SQp (gram->scale)  ->  OHp (attn->proj)
#define OB_Y    0ull
#define OB_GP   0ull
#define OB_SQP  4718592ull
#define OB_OHP  0ull
#define OB_Q    18874368ull
#define OB_K    23592960ull
#define OB_V    28311552ull
#define OB_L    33030144ull
#define OB_SC   33619968ull

typedef __bf16 bf16x8 __attribute__((ext_vector_type(8)));
typedef float f32x4 __attribute__((ext_vector_type(4)));
typedef float f32x16 __attribute__((ext_vector_type(16)));

__device__ __forceinline__ float bf2f(ushort u) {
  return __uint_as_float(((unsigned)u) << 16);
}
__device__ __forceinline__ ushort f2bf(float f) {
  __hip_bfloat16 h = __float2bfloat16(f);
  return *(ushort*)&h;
}
__device__ __forceinline__ void gload16(const void* g, void* l) {
  __builtin_amdgcn_global_load_lds((const __attribute__((address_space(1))) unsigned int*)g,
                                   (__attribute__((address_space(3))) unsigned int*)l, 16, 0, 0);
}

// ---------------- fused LayerNorm + 1x1 conv as bf16 MFMA GEMM ----------------
// grid (36, NB, 3); 4 waves; wave w: out-chs [64w,64w+64) x 64 px.
__global__ __launch_bounds__(256) void k_lnconv(const float* __restrict__ emb,
                                                const float* __restrict__ lw,
                                                const float* __restrict__ lb,
                                                const float* __restrict__ wq,
                                                const float* __restrict__ wk,
                                                const float* __restrict__ wv,
                                                ushort* __restrict__ Y) {
  __shared__ float Xs[64][68];   // [px][c]
  __shared__ float mu_s[64], rs_s[64], lw_s[64], lb_s[64];
  int p0 = blockIdx.x * 64, b = blockIdx.y, qkv = blockIdx.z;
  const float* Wm = qkv == 0 ? wq : (qkv == 1 ? wk : wv);
  const float* src = emb + (size_t)b * NC * NHW + p0;
  int t = threadIdx.x;
  for (int e = t; e < 1024; e += 256) {
    int c = e >> 4, p4 = (e & 15) * 4;
    float4 v = *(const float4*)&src[c * NHW + p4];
    Xs[p4][c] = v.x; Xs[p4 + 1][c] = v.y; Xs[p4 + 2][c] = v.z; Xs[p4 + 3][c] = v.w;
  }
  if (t < 64) { lw_s[t] = lw[t]; lb_s[t] = lb[t]; }
  __syncthreads();
  if (t < 64) {
    float s = 0.f, ss = 0.f;
#pragma unroll
    for (int c = 0; c < 64; c += 4) {
      float4 v = *(const float4*)&Xs[t][c];
      s += (v.x + v.y) + (v.z + v.w);
      ss += (v.x * v.x + v.y * v.y) + (v.z * v.z + v.w * v.w);
    }
    float m = s * (1.f / 64.f), va = ss * (1.f / 64.f) - m * m;
    mu_s[t] = m;
    rs_s[t] = rsqrtf(va + 1e-5f);
  }
  __syncthreads();
  int lane = t & 63, wvi = t >> 6, ql = lane & 31, h = lane >> 5;
  // B-frags (X): lane = px, k = c
  bf16x8 bfr[2][4];
#pragma unroll
  for (int pb = 0; pb < 2; ++pb) {
    int px = pb * 32 + ql;
    float mu = mu_s[px], rs = rs_s[px];
#pragma unroll
    for (int kc = 0; kc < 4; ++kc) {
      union { bf16x8 v; ushort u[8]; } pk;
#pragma unroll
      for (int j = 0; j < 8; ++j) {
        int c = kc * 16 + h * 8 + j;
        pk.u[j] = f2bf((Xs[px][c] - mu) * rs * lw_s[c] + lb_s[c]);
      }
      bfr[pb][kc] = pk.v;
    }
  }
  // A-frags (W): lane = out-ch row
  bf16x8 afr[2][4];
#pragma unroll
  for (int ob = 0; ob < 2; ++ob) {
    const float* wr = Wm + (size_t)(wvi * 64 + ob * 32 + ql) * 64;
#pragma unroll
    for (int kc = 0; kc < 4; ++kc) {
      union { bf16x8 v; ushort u[8]; } pk;
#pragma unroll
      for (int j = 0; j < 8; ++j) pk.u[j] = f2bf(wr[kc * 16 + h * 8 + j]);
      afr[ob][kc] = pk.v;
    }
  }
  f32x16 d00 = {}, d01 = {}, d10 = {}, d11 = {};
#pragma unroll
  for (int kc = 0; kc < 4; ++kc) {
    d00 = __builtin_amdgcn_mfma_f32_32x32x16_bf16(afr[0][kc], bfr[0][kc], d00, 0, 0, 0);
    d01 = __builtin_amdgcn_mfma_f32_32x32x16_bf16(afr[0][kc], bfr[1][kc], d01, 0, 0, 0);
    d10 = __builtin_amdgcn_mfma_f32_32x32x16_bf16(afr[1][kc], bfr[0][kc], d10, 0, 0, 0);
    d11 = __builtin_amdgcn_mfma_f32_32x32x16_bf16(afr[1][kc], bfr[1][kc], d11, 0, 0, 0);
  }
  ushort* dst = Y + ((size_t)(qkv * NB + b) * NCH + wvi * 64) * NHW + p0;
#pragma unroll
  for (int r = 0; r < 16; ++r) {
    int row = (r & 3) + 8 * (r >> 2) + 4 * h;
    dst[(size_t)row * NHW + ql] = f2bf(d00[r]);
    dst[(size_t)row * NHW + 32 + ql] = f2bf(d01[r]);
    dst[(size_t)(32 + row) * NHW + ql] = f2bf(d10[r]);
    dst[(size_t)(32 + row) * NHW + 32 + ql] = f2bf(d11[r]);
  }
}

// ---------------- depthwise 3x3 (q/k/v merged via grid.y), bf16 in/out ----------------
// Q/K out layout: [bh][cg=c>>3][n][8]   (attn-native, coalesced)
// V   out layout: [bh][mb=n>>3][c][8]
__global__ __launch_bounds__(256) void k_dw(const ushort* __restrict__ Y,
                                            const float* __restrict__ dwq,
                                            const float* __restrict__ dwk,
                                            const float* __restrict__ dwv,
                                            ushort* __restrict__ Qo,
                                            ushort* __restrict__ Ko,
                                            ushort* __restrict__ Vo) {
  __shared__ ushort Ys[64][3][48];
  __shared__ float Zs[64][49];
  __shared__ float Rs[48];
  int h = blockIdx.x;
  int hd = blockIdx.y & 3, qkv = blockIdx.y >> 2;
  int b = blockIdx.z;
  int bh = b * NHEADS + hd;
  const float* dwp = qkv == 0 ? dwq : (qkv == 1 ? dwk : dwv);
  const ushort* src = Y + ((size_t)(qkv * NB + b) * NCH + hd * 64) * NHW;
  for (int e = threadIdx.x; e < 64 * 3 * 12; e += 256) {
    int c = e / 36, rem = e % 36, r = rem / 12, w4 = (rem % 12) * 4;
    int hh = h + r - 1;
    ushort4 v = (hh >= 0 && hh < NH) ? *(const ushort4*)&src[c * NHW + hh * NW + w4]
                                     : make_ushort4(0, 0, 0, 0);
    *(ushort4*)&Ys[c][r][w4] = v;
  }
  __syncthreads();
  for (int e = threadIdx.x; e < 64 * 48; e += 256) {
    int c = e / 48, w = e % 48;
    const float* kk = dwp + ((size_t)hd * 64 + c) * 9;
    float acc = 0.f;
#pragma unroll
    for (int r = 0; r < 3; ++r)
#pragma unroll
      for (int dx = 0; dx < 3; ++dx) {
        int ww = w + dx - 1;
        float yv = (ww >= 0 && ww < NW) ? bf2f(Ys[c][r][ww]) : 0.f;
        acc += yv * kk[r * 3 + dx];
      }
    Zs[c][w] = acc;
  }
  __syncthreads();
  if (qkv < 2) {
    if (threadIdx.x < 48) {
      int w = threadIdx.x;
      float ss = 0.f;
#pragma unroll
      for (int c = 0; c < 64; ++c) { float z = Zs[c][w]; ss += z * z; }
      Rs[w] = 1.f / fmaxf(sqrtf(ss), 1e-12f);
    }
    __syncthreads();
    ushort* dst = (qkv == 0 ? Qo : Ko) + (size_t)bh * NHW * 64;
    for (int e = threadIdx.x; e < 48 * 16; e += 256) {
      int w = e >> 4, c4 = (e & 15) * 4;
      float rsc = Rs[w];
      ushort4 u = make_ushort4(f2bf(Zs[c4][w] * rsc), f2bf(Zs[c4 + 1][w] * rsc),
                               f2bf(Zs[c4 + 2][w] * rsc), f2bf(Zs[c4 + 3][w] * rsc));
      *(ushort4*)&dst[((size_t)(c4 >> 3) * NHW + h * NW + w) * 8 + (c4 & 7)] = u;
    }
  } else {
    ushort* dst = Vo + (size_t)bh * NHW * 64;
    for (int e = threadIdx.x; e < 64 * 12; e += 256) {
      int c = e / 12, w4 = (e % 12) * 4;
      ushort4 u = make_ushort4(f2bf(Zs[c][w4]), f2bf(Zs[c][w4 + 1]),
                               f2bf(Zs[c][w4 + 2]), f2bf(Zs[c][w4 + 3]));
      *(ushort4*)&dst[((size_t)(h * 6 + (w4 >> 3)) * 64 + c) * 8 + (w4 & 7)] = u;
    }
  }
}

// ---------------- gram partials via MFMA over LDS-transposed tiles ----------------
__global__ __launch_bounds__(256) void k_gram(const ushort* __restrict__ Q,
                                              const ushort* __restrict__ K,
                                              float* __restrict__ Gp,
                                              float* __restrict__ SQp) {
  __shared__ ushort Xt[64][72];   // [c][n] bf16
  int ns = blockIdx.x, qk = blockIdx.y, bh = blockIdx.z;
  const ushort* src = (qk ? K : Q) + (size_t)bh * NHW * 64;
  int t = threadIdx.x, lane = t & 63, wv = t >> 6;
  int lr = lane & 15, lg = lane >> 4;
  int ci0 = (wv >> 1) * 32, cj0 = (wv & 1) * 32;
  f32x4 acc[2][2];
#pragma unroll
  for (int i = 0; i < 2; ++i)
#pragma unroll
    for (int j = 0; j < 2; ++j) acc[i][j] = (f32x4){0.f, 0.f, 0.f, 0.f};
  float sq = 0.f;
  for (int it = 0; it < 4; ++it) {
    __syncthreads();
#pragma unroll
    for (int i2 = 0; i2 < 2; ++i2) {
      int n = t & 63, cg = (t >> 6) + 4 * i2;
      union { bf16x8 v; ushort u[8]; } ld;
      ld.v = *(const bf16x8*)&src[((size_t)cg * NHW + ns * 256 + it * 64 + n) * 8];
#pragma unroll
      for (int j = 0; j < 8; ++j) Xt[cg * 8 + j][n] = ld.u[j];
    }
    __syncthreads();
    if (t < 64) {
#pragma unroll
      for (int g = 0; g < 8; ++g) {
        union { bf16x8 v; ushort u[8]; } rd;
        rd.v = *(const bf16x8*)&Xt[t][g * 8];
#pragma unroll
        for (int j = 0; j < 8; ++j) sq += bf2f(rd.u[j]);
      }
    }
#pragma unroll
    for (int kh = 0; kh < 2; ++kh) {
      bf16x8 a0 = *(const bf16x8*)&Xt[ci0 + lr][kh * 32 + lg * 8];
      bf16x8 a1 = *(const bf16x8*)&Xt[ci0 + 16 + lr][kh * 32 + lg * 8];
      bf16x8 b0 = *(const bf16x8*)&Xt[cj0 + lr][kh * 32 + lg * 8];
      bf16x8 b1 = *(const bf16x8*)&Xt[cj0 + 16 + lr][kh * 32 + lg * 8];
      acc[0][0] = __builtin_amdgcn_mfma_f32_16x16x32_bf16(a0, b0, acc[0][0], 0, 0, 0);
      acc[0][1] = __builtin_amdgcn_mfma_f32_16x16x32_bf16(a0, b1, acc[0][1], 0, 0, 0);
      acc[1][0] = __builtin_amdgcn_mfma_f32_16x16x32_bf16(a1, b0, acc[1][0], 0, 0, 0);
      acc[1][1] = __builtin_amdgcn_mfma_f32_16x16x32_bf16(a1, b1, acc[1][1], 0, 0, 0);
    }
  }
  float* g = Gp + ((size_t)(ns * 2 + qk) * NBH + bh) * 4096;
#pragma unroll
  for (int ii = 0; ii < 2; ++ii)
#pragma unroll
    for (int jj = 0; jj < 2; ++jj)
#pragma unroll
      for (int r = 0; r < 4; ++r)
        g[(ci0 + ii * 16 + lg * 4 + r) * 64 + cj0 + jj * 16 + lr] = acc[ii][jj][r];
  if (t < 64) SQp[((size_t)(ns * 2 + qk) * NBH + bh) * 64 + t] = sq;
}

// ---------------- reduce partials -> per-(b,h) exp2 scale ----------------
__global__ __launch_bounds__(256) void k_scale(const float* __restrict__ Gp,
                                               const float* __restrict__ SQp,
                                               float* __restrict__ SC) {
  __shared__ float red[256];
  __shared__ float red2[64];
  int bh = blockIdx.x, t = threadIdx.x;
  float ssum = 0.f;
  for (int i = t; i < 4096; i += 256) {
    float gq = 0.f, gk = 0.f;
#pragma unroll
    for (int ns = 0; ns < 9; ++ns) {
      gq += Gp[((size_t)(ns * 2 + 0) * NBH + bh) * 4096 + i];
      gk += Gp[((size_t)(ns * 2 + 1) * NBH + bh) * 4096 + i];
    }
    ssum += gq * gk;
  }
  red[t] = ssum;
  if (t < 64) {
    float sq_q = 0.f, sq_k = 0.f;
#pragma unroll
    for (int ns = 0; ns < 9; ++ns) {
      sq_q += SQp[((size_t)(ns * 2 + 0) * NBH + bh) * 64 + t];
      sq_k += SQp[((size_t)(ns * 2 + 1) * NBH + bh) * 64 + t];
    }
    red2[t] = sq_q * sq_k;
  }
  __syncthreads();
  if (t == 0) {
    double S = 0.0, A = 0.0;
    for (int i = 0; i < 256; ++i) S += red[i];
    for (int i = 0; i < 64; ++i) A += red2[i];
    const double N2 = (double)NHW * (double)NHW;
    double mean = A / (N2 * 48.0);
    double ea2 = S / (N2 * 2304.0);
    double var = ea2 - mean * mean;
    SC[bh] = (float)((1.0 / sqrt(var + 1e-5)) / 48.0 * 1.4426950408889634);
  }
}

// ---------------- flash attention v6: XCD-clustered, 4-buffer counted-vmcnt pipeline ----
// grid (576) 1-D; physical block p -> XCD p%8; XCD g owns bh {2g,2g+1} (KV L2-resident).
// 4 waves; wave owns 64 q-rows x 576-m chunk. One s_barrier + vmcnt(4) per tile.
__global__ __launch_bounds__(256, 2) void k_attn(const ushort* __restrict__ Q,
                                                 const ushort* __restrict__ K,
                                                 const ushort* __restrict__ V,
                                                 const float* __restrict__ SC,
                                                 ushort* __restrict__ OHp,
                                                 float* __restrict__ Lp) {
  __shared__ ushort Kl[4][2048];
  __shared__ ushort Vl[4][2048];
  int p = blockIdx.x;
  int gb = p & 7;
  int w = p >> 3;          // 0..71
  int qt = w % 9;
  int rem = w / 9;         // 0..7
  int chunk = rem & 3;
  int bh = gb * 2 + (rem >> 2);
  int t = threadIdx.x, lane = t & 63, wv = t >> 6;
  int ql = lane & 31, h = lane >> 5;
  int q0 = qt * 256 + wv * 64;
  int m00 = chunk * CHUNK;
  const ushort* base = Q + (size_t)bh * NHW * 64;
  float sc2 = SC[bh];

  // Q fragments: 2 q-blocks x 4 k-chunks
  bf16x8 qfr[2][4];
#pragma unroll
  for (int qb = 0; qb < 2; ++qb)
#pragma unroll
    for (int kc = 0; kc < 4; ++kc)
      qfr[qb][kc] = *(const bf16x8*)&base[((size_t)(kc * 2 + h) * NHW + q0 + qb * 32 + ql) * 8];
  // drain Q loads so counted vmcnt below only sees staging ops
  asm volatile("s_waitcnt vmcnt(0)" ::: "memory");

  const ushort* kst = K + (size_t)bh * NHW * 64 + ((size_t)(wv * 2 + h) * NHW + m00 + ql) * 8;
  const ushort* vst = V + (size_t)bh * NHW * 64 + ((size_t)((m00 >> 3) + wv) * 64 + lane) * 8;

  f32x16 o[2][2];
#pragma unroll
  for (int qb = 0; qb < 2; ++qb) { o[qb][0] = (f32x16){}; o[qb][1] = (f32x16){}; }
  float lp[2] = {0.f, 0.f};

  auto COMPUTE = [&](int cb) {
    bf16x8 ka[4], vb[4];
#pragma unroll
    for (int i = 0; i < 4; ++i)
      ka[i] = *(const bf16x8*)&Kl[cb][(2 * i + h) * 256 + ql * 8];
    vb[0] = *(const bf16x8*)&Vl[cb][h * 512 + ql * 8];
    vb[1] = *(const bf16x8*)&Vl[cb][(2 + h) * 512 + ql * 8];
    vb[2] = *(const bf16x8*)&Vl[cb][h * 512 + (ql + 32) * 8];
    vb[3] = *(const bf16x8*)&Vl[cb][(2 + h) * 512 + (ql + 32) * 8];
#pragma unroll
    for (int qb = 0; qb < 2; ++qb) {
      f32x16 s = {};
      s = __builtin_amdgcn_mfma_f32_32x32x16_bf16(ka[0], qfr[qb][0], s, 0, 0, 0);
      s = __builtin_amdgcn_mfma_f32_32x32x16_bf16(ka[1], qfr[qb][1], s, 0, 0, 0);
      s = __builtin_amdgcn_mfma_f32_32x32x16_bf16(ka[2], qfr[qb][2], s, 0, 0, 0);
      s = __builtin_amdgcn_mfma_f32_32x32x16_bf16(ka[3], qfr[qb][3], s, 0, 0, 0);
      float pv[16];
#pragma unroll
      for (int r = 0; r < 16; ++r) {
        pv[r] = __builtin_exp2f(s[r] * sc2);
        lp[qb] += pv[r];
      }
      uint u[8];
#pragma unroll
      for (int i = 0; i < 8; ++i)
        u[i] = (__float_as_uint(pv[2 * i + 1]) & 0xffff0000u) | (__float_as_uint(pv[2 * i]) >> 16);
      asm volatile("v_permlane32_swap_b32 %0, %1" : "+v"(u[0]), "+v"(u[2]));
      asm volatile("v_permlane32_swap_b32 %0, %1" : "+v"(u[1]), "+v"(u[3]));
      asm volatile("v_permlane32_swap_b32 %0, %1" : "+v"(u[4]), "+v"(u[6]));
      asm volatile("v_permlane32_swap_b32 %0, %1" : "+v"(u[5]), "+v"(u[7]));
      union { uint uu[4]; bf16x8 v; } pa0, pa1;
      pa0.uu[0] = u[0]; pa0.uu[1] = u[1]; pa0.uu[2] = u[2]; pa0.uu[3] = u[3];
      pa1.uu[0] = u[4]; pa1.uu[1] = u[5]; pa1.uu[2] = u[6]; pa1.uu[3] = u[7];
      o[qb][0] = __builtin_amdgcn_mfma_f32_32x32x16_bf16(pa0.v, vb[0], o[qb][0], 0, 0, 0);
      o[qb][0] = __builtin_amdgcn_mfma_f32_32x32x16_bf16(pa1.v, vb[1], o[qb][0], 0, 0, 0);
      o[qb][1] = __builtin_amdgcn_mfma_f32_32x32x16_bf16(pa0.v, vb[2], o[qb][1], 0, 0, 0);
      o[qb][1] = __builtin_amdgcn_mfma_f32_32x32x16_bf16(pa1.v, vb[3], o[qb][1], 0, 0, 0);
    }
  };

  // prologue: stage tiles 0,1
  gload16(kst, (void*)&Kl[0][wv * 512]);
  gload16(vst, (void*)&Vl[0][wv * 512]);
  gload16(kst + 256, (void*)&Kl[1][wv * 512]);
  gload16(vst + 2048, (void*)&Vl[1][wv * 512]);

  for (int mt = 0; mt < NT - 2; ++mt) {
    int sb = (mt + 2) & 3;
    gload16(kst + (size_t)(mt + 2) * 256, (void*)&Kl[sb][wv * 512]);
    gload16(vst + (size_t)(mt + 2) * 2048, (void*)&Vl[sb][wv * 512]);
    asm volatile("s_waitcnt vmcnt(4)" ::: "memory");
    __builtin_amdgcn_s_barrier();
    COMPUTE(mt & 3);
  }
  asm volatile("s_waitcnt vmcnt(2)" ::: "memory");
  __builtin_amdgcn_s_barrier();
  COMPUTE((NT - 2) & 3);
  asm volatile("s_waitcnt vmcnt(0)" ::: "memory");
  __builtin_amdgcn_s_barrier();
  COMPUTE((NT - 1) & 3);

#pragma unroll
  for (int qb = 0; qb < 2; ++qb) {
    lp[qb] += __shfl_xor(lp[qb], 32);
    lp[qb] *= 0.99609375f;  // compensate bf16 truncation mean bias of P
  }
  if (h == 0) {
#pragma unroll
    for (int qb = 0; qb < 2; ++qb)
      Lp[(size_t)(chunk * NBH + bh) * NHW + q0 + qb * 32 + ql] = lp[qb];
  }
  ushort* od = OHp + ((size_t)(chunk * NBH + bh) * NHW + q0) * 64;
#pragma unroll
  for (int qb = 0; qb < 2; ++qb)
#pragma unroll
    for (int r = 0; r < 16; ++r) {
      int qrow = qb * 32 + (r & 3) + 8 * (r >> 2) + 4 * h;
      od[(size_t)qrow * 64 + ql] = f2bf(o[qb][0][r]);
      od[(size_t)qrow * 64 + 32 + ql] = f2bf(o[qb][1][r]);
    }
}

// ---------------- combine partials + head-mean + projection + residual ----------------
__global__ __launch_bounds__(256) void k_proj(const ushort* __restrict__ OHp,
                                              const float* __restrict__ Lp,
                                              const float* __restrict__ PW,
                                              const float* __restrict__ PB,
                                              const float* __restrict__ org,
                                              float* __restrict__ out) {
  __shared__ float Ls[4][4][16];
  __shared__ float linv[4][16];
  __shared__ float Ms[64][17];
  int p0 = blockIdx.x * 16, b = blockIdx.y;
  int t = threadIdx.x;
  {
    int ck = t >> 6, hd = (t >> 4) & 3, p = t & 15;
    Ls[ck][hd][p] = Lp[(size_t)(ck * NBH + b * 4 + hd) * NHW + p0 + p];
  }
  __syncthreads();
  if (t < 64) {
    int hd = t >> 4, p = t & 15;
    linv[hd][p] = 1.f / (Ls[0][hd][p] + Ls[1][hd][p] + Ls[2][hd][p] + Ls[3][hd][p]);
  }
  __syncthreads();
  {
    int p = t >> 4, c4 = (t & 15) * 4;
    float a0 = 0.f, a1 = 0.f, a2 = 0.f, a3 = 0.f;
#pragma unroll
    for (int hd = 0; hd < 4; ++hd) {
      float s0 = 0.f, s1 = 0.f, s2 = 0.f, s3 = 0.f;
#pragma unroll
      for (int ck = 0; ck < 4; ++ck) {
        ushort4 u = *(const ushort4*)&OHp[((size_t)(ck * NBH + b * 4 + hd) * NHW + p0 + p) * 64 + c4];
        s0 += bf2f(u.x); s1 += bf2f(u.y); s2 += bf2f(u.z); s3 += bf2f(u.w);
      }
      float li = linv[hd][p];
      a0 += s0 * li; a1 += s1 * li; a2 += s2 * li; a3 += s3 * li;
    }
    Ms[c4][p] = 0.25f * a0;
    Ms[c4 + 1][p] = 0.25f * a1;
    Ms[c4 + 2][p] = 0.25f * a2;
    Ms[c4 + 3][p] = 0.25f * a3;
  }
  __syncthreads();
  int p = t & 15, og = t >> 4;
  float acc[4];
#pragma unroll
  for (int i = 0; i < 4; ++i) acc[i] = PB[og * 4 + i];
  for (int c = 0; c < 64; ++c) {
    float xr = Ms[c][p];
#pragma unroll
    for (int i = 0; i < 4; ++i) acc[i] += PW[(og * 4 + i) * 64 + c] * xr;
  }
  const float* orgp = org + (size_t)b * NC * NHW + p0 + p;
  float* outp = out + (size_t)b * NC * NHW + p0 + p;
#pragma unroll
  for (int i = 0; i < 4; ++i) {
    int oc = og * 4 + i;
    outp[(size_t)oc * NHW] = orgp[(size_t)oc * NHW] + acc[i];
  }
}

extern "C" void kernel_launch(void* const* d_in, const int* in_sizes, int n_in,
                              void* d_out, int out_size, void* d_ws, size_t ws_size,
                              hipStream_t stream) {
  const float* emb = (const float*)d_in[0];
  const float* lnw = (const float*)d_in[1];
  const float* lnb = (const float*)d_in[2];
  const float* wq  = (const float*)d_in[3];
  const float* wk  = (const float*)d_in[4];
  const float* wv  = (const float*)d_in[5];
  const float* dwq = (const float*)d_in[6];
  const float* dwk = (const float*)d_in[7];
  const float* dwv = (const float*)d_in[8];
  const float* pw  = (const float*)d_in[9];
  const float* pb  = (const float*)d_in[10];
  char* ws = (char*)d_ws;
  ushort* Y   = (ushort*)(ws + OB_Y);
  float*  Gp  = (float*)(ws + OB_GP);
  float*  SQp = (float*)(ws + OB_SQP);
  ushort* OHp = (ushort*)(ws + OB_OHP);
  ushort* Qb  = (ushort*)(ws + OB_Q);
  ushort* Kb  = (ushort*)(ws + OB_K);
  ushort* Vb  = (ushort*)(ws + OB_V);
  float*  Lpt = (float*)(ws + OB_L);
  float*  SCp = (float*)(ws + OB_SC);
  float* out = (float*)d_out;

  k_lnconv<<<dim3(NHW / 64, NB, 3), 256, 0, stream>>>(emb, lnw, lnb, wq, wk, wv, Y);
  k_dw<<<dim3(NH, 12, NB), 256, 0, stream>>>(Y, dwq, dwk, dwv, Qb, Kb, Vb);
  k_gram<<<dim3(9, 2, NBH), 256, 0, stream>>>(Qb, Kb, Gp, SQp);
  k_scale<<<dim3(NBH), 256, 0, stream>>>(Gp, SQp, SCp);
  k_attn<<<dim3(576), 256, 0, stream>>>(Qb, Kb, Vb, SCp, OHp, Lpt);
  k_proj<<<dim3(NHW / 16, NB), 256, 0, stream>>>(OHp, Lpt, pw, pb, emb, out);
}

// Round 8
// 114.940 us; speedup vs baseline: 11.1285x; 1.0951x over previous
//
#include <hip/hip_runtime.h>
#include <hip/hip_bf16.h>
#include <math.h>

#define NB 4
#define NC 64
#define NH 48
#define NW 48
#define NHEADS 4
#define NCH 256
#define NHW 2304
#define NBH 16
#define NCHK 4
#define CHUNK 576
#define NT (CHUNK / 32)

// ws byte offsets. Region [0,18874368) is time-shared:
//   Y (lnconv->dw)  ->  Gp+SQp (gram->scale)  ->  OHp (attn->proj)
#define OB_Y    0ull
#define OB_GP   0ull
#define OB_SQP  4718592ull
#define OB_OHP  0ull
#define OB_Q    18874368ull
#define OB_K    23592960ull
#define OB_V    28311552ull
#define OB_L    33030144ull
#define OB_SC   33619968ull

typedef __bf16 bf16x8 __attribute__((ext_vector_type(8)));
typedef float f32x4 __attribute__((ext_vector_type(4)));
typedef float f32x16 __attribute__((ext_vector_type(16)));

__device__ __forceinline__ float bf2f(ushort u) {
  return __uint_as_float(((unsigned)u) << 16);
}
__device__ __forceinline__ ushort f2bf(float f) {
  __hip_bfloat16 h = __float2bfloat16(f);
  return *(ushort*)&h;
}
__device__ __forceinline__ void gload16(const void* g, void* l) {
  __builtin_amdgcn_global_load_lds((const __attribute__((address_space(1))) unsigned int*)g,
                                   (__attribute__((address_space(3))) unsigned int*)l, 16, 0, 0);
}

// ---------------- fused LayerNorm + 1x1 conv as bf16 MFMA GEMM ----------------
// grid (36, NB, 3); 4 waves; wave w: out-chs [64w,64w+64) x 64 px.
__global__ __launch_bounds__(256) void k_lnconv(const float* __restrict__ emb,
                                                const float* __restrict__ lw,
                                                const float* __restrict__ lb,
                                                const float* __restrict__ wq,
                                                const float* __restrict__ wk,
                                                const float* __restrict__ wv,
                                                ushort* __restrict__ Y) {
  __shared__ float Xs[64][68];   // [px][c]
  __shared__ float mu_s[64], rs_s[64], lw_s[64], lb_s[64];
  int p0 = blockIdx.x * 64, b = blockIdx.y, qkv = blockIdx.z;
  const float* Wm = qkv == 0 ? wq : (qkv == 1 ? wk : wv);
  const float* src = emb + (size_t)b * NC * NHW + p0;
  int t = threadIdx.x;
  for (int e = t; e < 1024; e += 256) {
    int c = e >> 4, p4 = (e & 15) * 4;
    float4 v = *(const float4*)&src[c * NHW + p4];
    Xs[p4][c] = v.x; Xs[p4 + 1][c] = v.y; Xs[p4 + 2][c] = v.z; Xs[p4 + 3][c] = v.w;
  }
  if (t < 64) { lw_s[t] = lw[t]; lb_s[t] = lb[t]; }
  __syncthreads();
  if (t < 64) {
    float s = 0.f, ss = 0.f;
#pragma unroll
    for (int c = 0; c < 64; c += 4) {
      float4 v = *(const float4*)&Xs[t][c];
      s += (v.x + v.y) + (v.z + v.w);
      ss += (v.x * v.x + v.y * v.y) + (v.z * v.z + v.w * v.w);
    }
    float m = s * (1.f / 64.f), va = ss * (1.f / 64.f) - m * m;
    mu_s[t] = m;
    rs_s[t] = rsqrtf(va + 1e-5f);
  }
  __syncthreads();
  int lane = t & 63, wvi = t >> 6, ql = lane & 31, h = lane >> 5;
  // B-frags (X): lane = px, k = c
  bf16x8 bfr[2][4];
#pragma unroll
  for (int pb = 0; pb < 2; ++pb) {
    int px = pb * 32 + ql;
    float mu = mu_s[px], rs = rs_s[px];
#pragma unroll
    for (int kc = 0; kc < 4; ++kc) {
      union { bf16x8 v; ushort u[8]; } pk;
#pragma unroll
      for (int j = 0; j < 8; ++j) {
        int c = kc * 16 + h * 8 + j;
        pk.u[j] = f2bf((Xs[px][c] - mu) * rs * lw_s[c] + lb_s[c]);
      }
      bfr[pb][kc] = pk.v;
    }
  }
  // A-frags (W): lane = out-ch row
  bf16x8 afr[2][4];
#pragma unroll
  for (int ob = 0; ob < 2; ++ob) {
    const float* wr = Wm + (size_t)(wvi * 64 + ob * 32 + ql) * 64;
#pragma unroll
    for (int kc = 0; kc < 4; ++kc) {
      union { bf16x8 v; ushort u[8]; } pk;
#pragma unroll
      for (int j = 0; j < 8; ++j) pk.u[j] = f2bf(wr[kc * 16 + h * 8 + j]);
      afr[ob][kc] = pk.v;
    }
  }
  f32x16 d00 = {}, d01 = {}, d10 = {}, d11 = {};
#pragma unroll
  for (int kc = 0; kc < 4; ++kc) {
    d00 = __builtin_amdgcn_mfma_f32_32x32x16_bf16(afr[0][kc], bfr[0][kc], d00, 0, 0, 0);
    d01 = __builtin_amdgcn_mfma_f32_32x32x16_bf16(afr[0][kc], bfr[1][kc], d01, 0, 0, 0);
    d10 = __builtin_amdgcn_mfma_f32_32x32x16_bf16(afr[1][kc], bfr[0][kc], d10, 0, 0, 0);
    d11 = __builtin_amdgcn_mfma_f32_32x32x16_bf16(afr[1][kc], bfr[1][kc], d11, 0, 0, 0);
  }
  ushort* dst = Y + ((size_t)(qkv * NB + b) * NCH + wvi * 64) * NHW + p0;
#pragma unroll
  for (int r = 0; r < 16; ++r) {
    int row = (r & 3) + 8 * (r >> 2) + 4 * h;
    dst[(size_t)row * NHW + ql] = f2bf(d00[r]);
    dst[(size_t)row * NHW + 32 + ql] = f2bf(d01[r]);
    dst[(size_t)(32 + row) * NHW + ql] = f2bf(d10[r]);
    dst[(size_t)(32 + row) * NHW + 32 + ql] = f2bf(d11[r]);
  }
}

// ---------------- depthwise 3x3 (q/k/v merged via grid.y), bf16 in/out ----------------
// Q/K out layout: [bh][cg=c>>3][n][8]   (attn-native, coalesced)
// V   out layout: [bh][mb=n>>3][c][8]
__global__ __launch_bounds__(256) void k_dw(const ushort* __restrict__ Y,
                                            const float* __restrict__ dwq,
                                            const float* __restrict__ dwk,
                                            const float* __restrict__ dwv,
                                            ushort* __restrict__ Qo,
                                            ushort* __restrict__ Ko,
                                            ushort* __restrict__ Vo) {
  __shared__ ushort Ys[64][3][48];
  __shared__ float Zs[64][49];
  __shared__ float Rs[48];
  int h = blockIdx.x;
  int hd = blockIdx.y & 3, qkv = blockIdx.y >> 2;
  int b = blockIdx.z;
  int bh = b * NHEADS + hd;
  const float* dwp = qkv == 0 ? dwq : (qkv == 1 ? dwk : dwv);
  const ushort* src = Y + ((size_t)(qkv * NB + b) * NCH + hd * 64) * NHW;
  for (int e = threadIdx.x; e < 64 * 3 * 12; e += 256) {
    int c = e / 36, rem = e % 36, r = rem / 12, w4 = (rem % 12) * 4;
    int hh = h + r - 1;
    ushort4 v = (hh >= 0 && hh < NH) ? *(const ushort4*)&src[c * NHW + hh * NW + w4]
                                     : make_ushort4(0, 0, 0, 0);
    *(ushort4*)&Ys[c][r][w4] = v;
  }
  __syncthreads();
  for (int e = threadIdx.x; e < 64 * 48; e += 256) {
    int c = e / 48, w = e % 48;
    const float* kk = dwp + ((size_t)hd * 64 + c) * 9;
    float acc = 0.f;
#pragma unroll
    for (int r = 0; r < 3; ++r)
#pragma unroll
      for (int dx = 0; dx < 3; ++dx) {
        int ww = w + dx - 1;
        float yv = (ww >= 0 && ww < NW) ? bf2f(Ys[c][r][ww]) : 0.f;
        acc += yv * kk[r * 3 + dx];
      }
    Zs[c][w] = acc;
  }
  __syncthreads();
  if (qkv < 2) {
    if (threadIdx.x < 48) {
      int w = threadIdx.x;
      float ss = 0.f;
#pragma unroll
      for (int c = 0; c < 64; ++c) { float z = Zs[c][w]; ss += z * z; }
      Rs[w] = 1.f / fmaxf(sqrtf(ss), 1e-12f);
    }
    __syncthreads();
    ushort* dst = (qkv == 0 ? Qo : Ko) + (size_t)bh * NHW * 64;
    for (int e = threadIdx.x; e < 48 * 16; e += 256) {
      int w = e >> 4, c4 = (e & 15) * 4;
      float rsc = Rs[w];
      ushort4 u = make_ushort4(f2bf(Zs[c4][w] * rsc), f2bf(Zs[c4 + 1][w] * rsc),
                               f2bf(Zs[c4 + 2][w] * rsc), f2bf(Zs[c4 + 3][w] * rsc));
      *(ushort4*)&dst[((size_t)(c4 >> 3) * NHW + h * NW + w) * 8 + (c4 & 7)] = u;
    }
  } else {
    ushort* dst = Vo + (size_t)bh * NHW * 64;
    for (int e = threadIdx.x; e < 64 * 12; e += 256) {
      int c = e / 12, w4 = (e % 12) * 4;
      ushort4 u = make_ushort4(f2bf(Zs[c][w4]), f2bf(Zs[c][w4 + 1]),
                               f2bf(Zs[c][w4 + 2]), f2bf(Zs[c][w4 + 3]));
      *(ushort4*)&dst[((size_t)(h * 6 + (w4 >> 3)) * 64 + c) * 8 + (w4 & 7)] = u;
    }
  }
}

// ---------------- gram partials via MFMA over LDS-transposed tiles ----------------
__global__ __launch_bounds__(256) void k_gram(const ushort* __restrict__ Q,
                                              const ushort* __restrict__ K,
                                              float* __restrict__ Gp,
                                              float* __restrict__ SQp) {
  __shared__ ushort Xt[64][72];   // [c][n] bf16
  int ns = blockIdx.x, qk = blockIdx.y, bh = blockIdx.z;
  const ushort* src = (qk ? K : Q) + (size_t)bh * NHW * 64;
  int t = threadIdx.x, lane = t & 63, wv = t >> 6;
  int lr = lane & 15, lg = lane >> 4;
  int ci0 = (wv >> 1) * 32, cj0 = (wv & 1) * 32;
  f32x4 acc[2][2];
#pragma unroll
  for (int i = 0; i < 2; ++i)
#pragma unroll
    for (int j = 0; j < 2; ++j) acc[i][j] = (f32x4){0.f, 0.f, 0.f, 0.f};
  float sq = 0.f;
  for (int it = 0; it < 4; ++it) {
    __syncthreads();
#pragma unroll
    for (int i2 = 0; i2 < 2; ++i2) {
      int n = t & 63, cg = (t >> 6) + 4 * i2;
      union { bf16x8 v; ushort u[8]; } ld;
      ld.v = *(const bf16x8*)&src[((size_t)cg * NHW + ns * 256 + it * 64 + n) * 8];
#pragma unroll
      for (int j = 0; j < 8; ++j) Xt[cg * 8 + j][n] = ld.u[j];
    }
    __syncthreads();
    if (t < 64) {
#pragma unroll
      for (int g = 0; g < 8; ++g) {
        union { bf16x8 v; ushort u[8]; } rd;
        rd.v = *(const bf16x8*)&Xt[t][g * 8];
#pragma unroll
        for (int j = 0; j < 8; ++j) sq += bf2f(rd.u[j]);
      }
    }
#pragma unroll
    for (int kh = 0; kh < 2; ++kh) {
      bf16x8 a0 = *(const bf16x8*)&Xt[ci0 + lr][kh * 32 + lg * 8];
      bf16x8 a1 = *(const bf16x8*)&Xt[ci0 + 16 + lr][kh * 32 + lg * 8];
      bf16x8 b0 = *(const bf16x8*)&Xt[cj0 + lr][kh * 32 + lg * 8];
      bf16x8 b1 = *(const bf16x8*)&Xt[cj0 + 16 + lr][kh * 32 + lg * 8];
      acc[0][0] = __builtin_amdgcn_mfma_f32_16x16x32_bf16(a0, b0, acc[0][0], 0, 0, 0);
      acc[0][1] = __builtin_amdgcn_mfma_f32_16x16x32_bf16(a0, b1, acc[0][1], 0, 0, 0);
      acc[1][0] = __builtin_amdgcn_mfma_f32_16x16x32_bf16(a1, b0, acc[1][0], 0, 0, 0);
      acc[1][1] = __builtin_amdgcn_mfma_f32_16x16x32_bf16(a1, b1, acc[1][1], 0, 0, 0);
    }
  }
  float* g = Gp + ((size_t)(ns * 2 + qk) * NBH + bh) * 4096;
#pragma unroll
  for (int ii = 0; ii < 2; ++ii)
#pragma unroll
    for (int jj = 0; jj < 2; ++jj)
#pragma unroll
      for (int r = 0; r < 4; ++r)
        g[(ci0 + ii * 16 + lg * 4 + r) * 64 + cj0 + jj * 16 + lr] = acc[ii][jj][r];
  if (t < 64) SQp[((size_t)(ns * 2 + qk) * NBH + bh) * 64 + t] = sq;
}

// ---------------- reduce partials -> per-(b,h) exp2 scale ----------------
__global__ __launch_bounds__(256) void k_scale(const float* __restrict__ Gp,
                                               const float* __restrict__ SQp,
                                               float* __restrict__ SC) {
  __shared__ float red[256];
  __shared__ float red2[64];
  int bh = blockIdx.x, t = threadIdx.x;
  float ssum = 0.f;
  for (int i = t; i < 4096; i += 256) {
    float gq = 0.f, gk = 0.f;
#pragma unroll
    for (int ns = 0; ns < 9; ++ns) {
      gq += Gp[((size_t)(ns * 2 + 0) * NBH + bh) * 4096 + i];
      gk += Gp[((size_t)(ns * 2 + 1) * NBH + bh) * 4096 + i];
    }
    ssum += gq * gk;
  }
  red[t] = ssum;
  if (t < 64) {
    float sq_q = 0.f, sq_k = 0.f;
#pragma unroll
    for (int ns = 0; ns < 9; ++ns) {
      sq_q += SQp[((size_t)(ns * 2 + 0) * NBH + bh) * 64 + t];
      sq_k += SQp[((size_t)(ns * 2 + 1) * NBH + bh) * 64 + t];
    }
    red2[t] = sq_q * sq_k;
  }
  __syncthreads();
  if (t == 0) {
    double S = 0.0, A = 0.0;
    for (int i = 0; i < 256; ++i) S += red[i];
    for (int i = 0; i < 64; ++i) A += red2[i];
    const double N2 = (double)NHW * (double)NHW;
    double mean = A / (N2 * 48.0);
    double ea2 = S / (N2 * 2304.0);
    double var = ea2 - mean * mean;
    SC[bh] = (float)((1.0 / sqrt(var + 1e-5)) / 48.0 * 1.4426950408889634);
  }
}

// ---------------- flash attention v7: 1152 blocks, 32 q/wave, cvt_pk, setprio ----------
// grid (1152) 1-D; physical block p -> XCD p%8; XCD g owns bh {2g,2g+1}.
// 4 waves; wave owns 32 q-rows x 576-m chunk. 4 LDS buffers, vmcnt(4)+1 barrier/tile.
__global__ __launch_bounds__(256, 2) void k_attn(const ushort* __restrict__ Q,
                                                 const ushort* __restrict__ K,
                                                 const ushort* __restrict__ V,
                                                 const float* __restrict__ SC,
                                                 ushort* __restrict__ OHp,
                                                 float* __restrict__ Lp) {
  __shared__ ushort Kl[4][2048];
  __shared__ ushort Vl[4][2048];
  int p = blockIdx.x;
  int gb = p & 7;
  int w = p >> 3;          // 0..143
  int qt = w % 18;
  int rem = w / 18;        // 0..7
  int chunk = rem & 3;
  int bh = gb * 2 + (rem >> 2);
  int t = threadIdx.x, lane = t & 63, wv = t >> 6;
  int ql = lane & 31, h = lane >> 5;
  int q0 = qt * 128 + wv * 32;
  int m00 = chunk * CHUNK;
  const ushort* base = Q + (size_t)bh * NHW * 64;
  float sc2 = SC[bh];

  // Q fragments: 4 k-chunks (32 q-rows)
  bf16x8 qfr[4];
#pragma unroll
  for (int kc = 0; kc < 4; ++kc)
    qfr[kc] = *(const bf16x8*)&base[((size_t)(kc * 2 + h) * NHW + q0 + ql) * 8];
  // drain Q loads so counted vmcnt below only sees staging ops
  asm volatile("s_waitcnt vmcnt(0)" ::: "memory");

  const ushort* kst = K + (size_t)bh * NHW * 64 + ((size_t)(wv * 2 + h) * NHW + m00 + ql) * 8;
  const ushort* vst = V + (size_t)bh * NHW * 64 + ((size_t)((m00 >> 3) + wv) * 64 + lane) * 8;

  f32x16 o0 = {}, o1 = {};
  float lp = 0.f;

  auto COMPUTE = [&](int cb) {
    bf16x8 ka[4], vb[4];
#pragma unroll
    for (int i = 0; i < 4; ++i)
      ka[i] = *(const bf16x8*)&Kl[cb][(2 * i + h) * 256 + ql * 8];
    vb[0] = *(const bf16x8*)&Vl[cb][h * 512 + ql * 8];
    vb[1] = *(const bf16x8*)&Vl[cb][(2 + h) * 512 + ql * 8];
    vb[2] = *(const bf16x8*)&Vl[cb][h * 512 + (ql + 32) * 8];
    vb[3] = *(const bf16x8*)&Vl[cb][(2 + h) * 512 + (ql + 32) * 8];
    __builtin_amdgcn_s_setprio(1);
    f32x16 s = {};
    s = __builtin_amdgcn_mfma_f32_32x32x16_bf16(ka[0], qfr[0], s, 0, 0, 0);
    s = __builtin_amdgcn_mfma_f32_32x32x16_bf16(ka[1], qfr[1], s, 0, 0, 0);
    s = __builtin_amdgcn_mfma_f32_32x32x16_bf16(ka[2], qfr[2], s, 0, 0, 0);
    s = __builtin_amdgcn_mfma_f32_32x32x16_bf16(ka[3], qfr[3], s, 0, 0, 0);
    __builtin_amdgcn_s_setprio(0);
    float pv[16];
    float l0 = 0.f, l1 = 0.f, l2 = 0.f, l3 = 0.f;
#pragma unroll
    for (int r = 0; r < 16; r += 4) {
      pv[r] = __builtin_exp2f(s[r] * sc2);
      pv[r + 1] = __builtin_exp2f(s[r + 1] * sc2);
      pv[r + 2] = __builtin_exp2f(s[r + 2] * sc2);
      pv[r + 3] = __builtin_exp2f(s[r + 3] * sc2);
      l0 += pv[r]; l1 += pv[r + 1]; l2 += pv[r + 2]; l3 += pv[r + 3];
    }
    lp += (l0 + l1) + (l2 + l3);
    uint u[8];
#pragma unroll
    for (int i = 0; i < 8; ++i)
      asm("v_cvt_pk_bf16_f32 %0, %1, %2" : "=v"(u[i]) : "v"(pv[2 * i]), "v"(pv[2 * i + 1]));
    asm volatile("v_permlane32_swap_b32 %0, %1" : "+v"(u[0]), "+v"(u[2]));
    asm volatile("v_permlane32_swap_b32 %0, %1" : "+v"(u[1]), "+v"(u[3]));
    asm volatile("v_permlane32_swap_b32 %0, %1" : "+v"(u[4]), "+v"(u[6]));
    asm volatile("v_permlane32_swap_b32 %0, %1" : "+v"(u[5]), "+v"(u[7]));
    union { uint uu[4]; bf16x8 v; } pa0, pa1;
    pa0.uu[0] = u[0]; pa0.uu[1] = u[1]; pa0.uu[2] = u[2]; pa0.uu[3] = u[3];
    pa1.uu[0] = u[4]; pa1.uu[1] = u[5]; pa1.uu[2] = u[6]; pa1.uu[3] = u[7];
    __builtin_amdgcn_s_setprio(1);
    o0 = __builtin_amdgcn_mfma_f32_32x32x16_bf16(pa0.v, vb[0], o0, 0, 0, 0);
    o0 = __builtin_amdgcn_mfma_f32_32x32x16_bf16(pa1.v, vb[1], o0, 0, 0, 0);
    o1 = __builtin_amdgcn_mfma_f32_32x32x16_bf16(pa0.v, vb[2], o1, 0, 0, 0);
    o1 = __builtin_amdgcn_mfma_f32_32x32x16_bf16(pa1.v, vb[3], o1, 0, 0, 0);
    __builtin_amdgcn_s_setprio(0);
  };

  // prologue: stage tiles 0,1
  gload16(kst, (void*)&Kl[0][wv * 512]);
  gload16(vst, (void*)&Vl[0][wv * 512]);
  gload16(kst + 256, (void*)&Kl[1][wv * 512]);
  gload16(vst + 2048, (void*)&Vl[1][wv * 512]);

  for (int mt = 0; mt < NT - 2; ++mt) {
    int sb = (mt + 2) & 3;
    gload16(kst + (size_t)(mt + 2) * 256, (void*)&Kl[sb][wv * 512]);
    gload16(vst + (size_t)(mt + 2) * 2048, (void*)&Vl[sb][wv * 512]);
    asm volatile("s_waitcnt vmcnt(4)" ::: "memory");
    __builtin_amdgcn_s_barrier();
    COMPUTE(mt & 3);
  }
  asm volatile("s_waitcnt vmcnt(2)" ::: "memory");
  __builtin_amdgcn_s_barrier();
  COMPUTE((NT - 2) & 3);
  asm volatile("s_waitcnt vmcnt(0)" ::: "memory");
  __builtin_amdgcn_s_barrier();
  COMPUTE((NT - 1) & 3);

  lp += __shfl_xor(lp, 32);
  if (h == 0) Lp[(size_t)(chunk * NBH + bh) * NHW + q0 + ql] = lp;
  ushort* od = OHp + ((size_t)(chunk * NBH + bh) * NHW + q0) * 64;
#pragma unroll
  for (int r = 0; r < 16; ++r) {
    int qrow = (r & 3) + 8 * (r >> 2) + 4 * h;
    od[(size_t)qrow * 64 + ql] = f2bf(o0[r]);
    od[(size_t)qrow * 64 + 32 + ql] = f2bf(o1[r]);
  }
}

// ---------------- combine partials + head-mean + projection + residual ----------------
__global__ __launch_bounds__(256) void k_proj(const ushort* __restrict__ OHp,
                                              const float* __restrict__ Lp,
                                              const float* __restrict__ PW,
                                              const float* __restrict__ PB,
                                              const float* __restrict__ org,
                                              float* __restrict__ out) {
  __shared__ float Ls[4][4][16];
  __shared__ float linv[4][16];
  __shared__ float Ms[64][17];
  int p0 = blockIdx.x * 16, b = blockIdx.y;
  int t = threadIdx.x;
  {
    int ck = t >> 6, hd = (t >> 4) & 3, p = t & 15;
    Ls[ck][hd][p] = Lp[(size_t)(ck * NBH + b * 4 + hd) * NHW + p0 + p];
  }
  __syncthreads();
  if (t < 64) {
    int hd = t >> 4, p = t & 15;
    linv[hd][p] = 1.f / (Ls[0][hd][p] + Ls[1][hd][p] + Ls[2][hd][p] + Ls[3][hd][p]);
  }
  __syncthreads();
  {
    int p = t >> 4, c4 = (t & 15) * 4;
    float a0 = 0.f, a1 = 0.f, a2 = 0.f, a3 = 0.f;
#pragma unroll
    for (int hd = 0; hd < 4; ++hd) {
      float s0 = 0.f, s1 = 0.f, s2 = 0.f, s3 = 0.f;
#pragma unroll
      for (int ck = 0; ck < 4; ++ck) {
        ushort4 u = *(const ushort4*)&OHp[((size_t)(ck * NBH + b * 4 + hd) * NHW + p0 + p) * 64 + c4];
        s0 += bf2f(u.x); s1 += bf2f(u.y); s2 += bf2f(u.z); s3 += bf2f(u.w);
      }
      float li = linv[hd][p];
      a0 += s0 * li; a1 += s1 * li; a2 += s2 * li; a3 += s3 * li;
    }
    Ms[c4][p] = 0.25f * a0;
    Ms[c4 + 1][p] = 0.25f * a1;
    Ms[c4 + 2][p] = 0.25f * a2;
    Ms[c4 + 3][p] = 0.25f * a3;
  }
  __syncthreads();
  int p = t & 15, og = t >> 4;
  float acc[4];
#pragma unroll
  for (int i = 0; i < 4; ++i) acc[i] = PB[og * 4 + i];
  for (int c = 0; c < 64; ++c) {
    float xr = Ms[c][p];
#pragma unroll
    for (int i = 0; i < 4; ++i) acc[i] += PW[(og * 4 + i) * 64 + c] * xr;
  }
  const float* orgp = org + (size_t)b * NC * NHW + p0 + p;
  float* outp = out + (size_t)b * NC * NHW + p0 + p;
#pragma unroll
  for (int i = 0; i < 4; ++i) {
    int oc = og * 4 + i;
    outp[(size_t)oc * NHW] = orgp[(size_t)oc * NHW] + acc[i];
  }
}

extern "C" void kernel_launch(void* const* d_in, const int* in_sizes, int n_in,
                              void* d_out, int out_size, void* d_ws, size_t ws_size,
                              hipStream_t stream) {
  const float* emb = (const float*)d_in[0];
  const float* lnw = (const float*)d_in[1];
  const float* lnb = (const float*)d_in[2];
  const float* wq  = (const float*)d_in[3];
  const float* wk  = (const float*)d_in[4];
  const float* wv  = (const float*)d_in[5];
  const float* dwq = (const float*)d_in[6];
  const float* dwk = (const float*)d_in[7];
  const float* dwv = (const float*)d_in[8];
  const float* pw  = (const float*)d_in[9];
  const float* pb  = (const float*)d_in[10];
  char* ws = (char*)d_ws;
  ushort* Y   = (ushort*)(ws + OB_Y);
  float*  Gp  = (float*)(ws + OB_GP);
  float*  SQp = (float*)(ws + OB_SQP);
  ushort* OHp = (ushort*)(ws + OB_OHP);
  ushort* Qb  = (ushort*)(ws + OB_Q);
  ushort* Kb  = (ushort*)(ws + OB_K);
  ushort* Vb  = (ushort*)(ws + OB_V);
  float*  Lpt = (float*)(ws + OB_L);
  float*  SCp = (float*)(ws + OB_SC);
  float* out = (float*)d_out;

  k_lnconv<<<dim3(NHW / 64, NB, 3), 256, 0, stream>>>(emb, lnw, lnb, wq, wk, wv, Y);
  k_dw<<<dim3(NH, 12, NB), 256, 0, stream>>>(Y, dwq, dwk, dwv, Qb, Kb, Vb);
  k_gram<<<dim3(9, 2, NBH), 256, 0, stream>>>(Qb, Kb, Gp, SQp);
  k_scale<<<dim3(NBH), 256, 0, stream>>>(Gp, SQp, SCp);
  k_attn<<<dim3(1152), 256, 0, stream>>>(Qb, Kb, Vb, SCp, OHp, Lpt);
  k_proj<<<dim3(NHW / 16, NB), 256, 0, stream>>>(OHp, Lpt, pw, pb, emb, out);
}

// Round 9
// 108.746 us; speedup vs baseline: 11.7623x; 1.0570x over previous
//
#include <hip/hip_runtime.h>
#include <hip/hip_bf16.h>
#include <math.h>

#define NB 4
#define NC 64
#define NH 48
#define NW 48
#define NHEADS 4
#define NCH 256
#define NHW 2304
#define NBH 16
#define NCHK 4
#define CHUNK 576
#define NT (CHUNK / 32)

// ws byte offsets. Region [0,18874368) is time-shared:
//   Y (lnconv->dw) -> G+SQ (gram->scale) -> OHp (attn->proj)
#define OB_Y    0ull
#define OB_G    0ull
#define OB_SQ   524288ull
#define OB_OHP  0ull
#define OB_Q    18874368ull
#define OB_K    23592960ull
#define OB_V    28311552ull
#define OB_L    33030144ull
#define OB_SC   33619968ull

typedef __bf16 bf16x8 __attribute__((ext_vector_type(8)));
typedef float f32x4 __attribute__((ext_vector_type(4)));
typedef float f32x16 __attribute__((ext_vector_type(16)));

__device__ __forceinline__ float bf2f(ushort u) {
  return __uint_as_float(((unsigned)u) << 16);
}
__device__ __forceinline__ ushort f2bf(float f) {
  __hip_bfloat16 h = __float2bfloat16(f);
  return *(ushort*)&h;
}
__device__ __forceinline__ void gload16(const void* g, void* l) {
  __builtin_amdgcn_global_load_lds((const __attribute__((address_space(1))) unsigned int*)g,
                                   (__attribute__((address_space(3))) unsigned int*)l, 16, 0, 0);
}

// ---------------- fused LayerNorm + 1x1 conv as bf16 MFMA GEMM ----------------
__global__ __launch_bounds__(256) void k_lnconv(const float* __restrict__ emb,
                                                const float* __restrict__ lw,
                                                const float* __restrict__ lb,
                                                const float* __restrict__ wq,
                                                const float* __restrict__ wk,
                                                const float* __restrict__ wv,
                                                ushort* __restrict__ Y) {
  __shared__ float Xs[64][68];   // [px][c]
  __shared__ float mu_s[64], rs_s[64], lw_s[64], lb_s[64];
  int p0 = blockIdx.x * 64, b = blockIdx.y, qkv = blockIdx.z;
  const float* Wm = qkv == 0 ? wq : (qkv == 1 ? wk : wv);
  const float* src = emb + (size_t)b * NC * NHW + p0;
  int t = threadIdx.x;
  for (int e = t; e < 1024; e += 256) {
    int c = e >> 4, p4 = (e & 15) * 4;
    float4 v = *(const float4*)&src[c * NHW + p4];
    Xs[p4][c] = v.x; Xs[p4 + 1][c] = v.y; Xs[p4 + 2][c] = v.z; Xs[p4 + 3][c] = v.w;
  }
  if (t < 64) { lw_s[t] = lw[t]; lb_s[t] = lb[t]; }
  __syncthreads();
  if (t < 64) {
    float s = 0.f, ss = 0.f;
#pragma unroll
    for (int c = 0; c < 64; c += 4) {
      float4 v = *(const float4*)&Xs[t][c];
      s += (v.x + v.y) + (v.z + v.w);
      ss += (v.x * v.x + v.y * v.y) + (v.z * v.z + v.w * v.w);
    }
    float m = s * (1.f / 64.f), va = ss * (1.f / 64.f) - m * m;
    mu_s[t] = m;
    rs_s[t] = rsqrtf(va + 1e-5f);
  }
  __syncthreads();
  int lane = t & 63, wvi = t >> 6, ql = lane & 31, h = lane >> 5;
  bf16x8 bfr[2][4];
#pragma unroll
  for (int pb = 0; pb < 2; ++pb) {
    int px = pb * 32 + ql;
    float mu = mu_s[px], rs = rs_s[px];
#pragma unroll
    for (int kc = 0; kc < 4; ++kc) {
      union { bf16x8 v; ushort u[8]; } pk;
#pragma unroll
      for (int j = 0; j < 8; ++j) {
        int c = kc * 16 + h * 8 + j;
        pk.u[j] = f2bf((Xs[px][c] - mu) * rs * lw_s[c] + lb_s[c]);
      }
      bfr[pb][kc] = pk.v;
    }
  }
  bf16x8 afr[2][4];
#pragma unroll
  for (int ob = 0; ob < 2; ++ob) {
    const float* wr = Wm + (size_t)(wvi * 64 + ob * 32 + ql) * 64;
#pragma unroll
    for (int kc = 0; kc < 4; ++kc) {
      union { bf16x8 v; ushort u[8]; } pk;
#pragma unroll
      for (int j = 0; j < 8; ++j) pk.u[j] = f2bf(wr[kc * 16 + h * 8 + j]);
      afr[ob][kc] = pk.v;
    }
  }
  f32x16 d00 = {}, d01 = {}, d10 = {}, d11 = {};
#pragma unroll
  for (int kc = 0; kc < 4; ++kc) {
    d00 = __builtin_amdgcn_mfma_f32_32x32x16_bf16(afr[0][kc], bfr[0][kc], d00, 0, 0, 0);
    d01 = __builtin_amdgcn_mfma_f32_32x32x16_bf16(afr[0][kc], bfr[1][kc], d01, 0, 0, 0);
    d10 = __builtin_amdgcn_mfma_f32_32x32x16_bf16(afr[1][kc], bfr[0][kc], d10, 0, 0, 0);
    d11 = __builtin_amdgcn_mfma_f32_32x32x16_bf16(afr[1][kc], bfr[1][kc], d11, 0, 0, 0);
  }
  ushort* dst = Y + ((size_t)(qkv * NB + b) * NCH + wvi * 64) * NHW + p0;
#pragma unroll
  for (int r = 0; r < 16; ++r) {
    int row = (r & 3) + 8 * (r >> 2) + 4 * h;
    dst[(size_t)row * NHW + ql] = f2bf(d00[r]);
    dst[(size_t)row * NHW + 32 + ql] = f2bf(d01[r]);
    dst[(size_t)(32 + row) * NHW + ql] = f2bf(d10[r]);
    dst[(size_t)(32 + row) * NHW + 32 + ql] = f2bf(d11[r]);
  }
}

// ---------------- depthwise 3x3, vectorized sliding-window conv ----------------
// Q/K out: [bh][cg=c>>3][n][8] ; V out: [bh][mb=n>>3][c][8]
__global__ __launch_bounds__(256) void k_dw(const ushort* __restrict__ Y,
                                            const float* __restrict__ dwq,
                                            const float* __restrict__ dwk,
                                            const float* __restrict__ dwv,
                                            ushort* __restrict__ Qo,
                                            ushort* __restrict__ Ko,
                                            ushort* __restrict__ Vo) {
  __shared__ ushort Ys[64][3][48];
  __shared__ float Zs[64][50];
  __shared__ float Ks9[64][9];
  __shared__ float Rp[4][48];
  __shared__ float Rs[48];
  int h = blockIdx.x;
  int hd = blockIdx.y & 3, qkv = blockIdx.y >> 2;
  int b = blockIdx.z;
  int bh = b * NHEADS + hd;
  const float* dwp = qkv == 0 ? dwq : (qkv == 1 ? dwk : dwv);
  const ushort* src = Y + ((size_t)(qkv * NB + b) * NCH + hd * 64) * NHW;
  int t = threadIdx.x;
  for (int e = t; e < 576; e += 256) Ks9[e / 9][e % 9] = dwp[(size_t)hd * 576 + e];
  for (int e = t; e < 2304; e += 256) {
    int c = e / 36, rem = e % 36, r = rem / 12, w4 = (rem % 12) * 4;
    int hh = h + r - 1;
    ushort4 v = (hh >= 0 && hh < NH) ? *(const ushort4*)&src[c * NHW + hh * NW + w4]
                                     : make_ushort4(0, 0, 0, 0);
    *(ushort4*)&Ys[c][r][w4] = v;
  }
  __syncthreads();
  for (int e = t; e < 768; e += 256) {
    int c = e / 12, w4 = (e % 12) * 4;
    float acc0 = 0.f, acc1 = 0.f, acc2 = 0.f, acc3 = 0.f;
#pragma unroll
    for (int r = 0; r < 3; ++r) {
      const ushort* row = &Ys[c][r][0];
      int li = w4 >= 4 ? w4 - 4 : 0;
      int ri = w4 <= 40 ? w4 + 4 : 40;
      uint2 L = *(const uint2*)&row[li];
      uint2 M = *(const uint2*)&row[w4];
      uint2 R = *(const uint2*)&row[ri];
      float vm1 = (w4 == 0) ? 0.f : __uint_as_float(L.y & 0xffff0000u);
      float m0 = __uint_as_float(M.x << 16);
      float m1 = __uint_as_float(M.x & 0xffff0000u);
      float m2 = __uint_as_float(M.y << 16);
      float m3 = __uint_as_float(M.y & 0xffff0000u);
      float v4 = (w4 == 44) ? 0.f : __uint_as_float(R.x << 16);
      float k0 = Ks9[c][r * 3], k1 = Ks9[c][r * 3 + 1], k2 = Ks9[c][r * 3 + 2];
      acc0 += vm1 * k0 + m0 * k1 + m1 * k2;
      acc1 += m0 * k0 + m1 * k1 + m2 * k2;
      acc2 += m1 * k0 + m2 * k1 + m3 * k2;
      acc3 += m2 * k0 + m3 * k1 + v4 * k2;
    }
    *(float2*)&Zs[c][w4] = make_float2(acc0, acc1);
    *(float2*)&Zs[c][w4 + 2] = make_float2(acc2, acc3);
  }
  __syncthreads();
  if (qkv < 2) {
    if (t < 192) {
      int cq = t / 48, w = t % 48;
      float ss = 0.f;
#pragma unroll
      for (int i = 0; i < 16; ++i) { float z = Zs[cq * 16 + i][w]; ss += z * z; }
      Rp[cq][w] = ss;
    }
    __syncthreads();
    if (t < 48)
      Rs[t] = 1.f / fmaxf(sqrtf(Rp[0][t] + Rp[1][t] + Rp[2][t] + Rp[3][t]), 1e-12f);
    __syncthreads();
    ushort* dst = (qkv == 0 ? Qo : Ko) + (size_t)bh * NHW * 64;
    for (int e = t; e < 768; e += 256) {
      int w = e >> 4, c4 = (e & 15) * 4;
      float rsc = Rs[w];
      ushort4 u = make_ushort4(f2bf(Zs[c4][w] * rsc), f2bf(Zs[c4 + 1][w] * rsc),
                               f2bf(Zs[c4 + 2][w] * rsc), f2bf(Zs[c4 + 3][w] * rsc));
      *(ushort4*)&dst[((size_t)(c4 >> 3) * NHW + h * NW + w) * 8 + (c4 & 7)] = u;
    }
  } else {
    ushort* dst = Vo + (size_t)bh * NHW * 64;
    for (int e = t; e < 768; e += 256) {
      int c = e / 12, w4 = (e % 12) * 4;
      float4 z = *(const float4*)&Zs[c][w4];
      ushort4 u = make_ushort4(f2bf(z.x), f2bf(z.y), f2bf(z.z), f2bf(z.w));
      *(ushort4*)&dst[((size_t)(h * 6 + (w4 >> 3)) * 64 + c) * 8 + (w4 & 7)] = u;
    }
  }
}

// ---------------- gram via MFMA, atomic accumulation into single G ----------------
// grid (9, 2, 16). G [2][16][4096] f32 (memset 0 first), SQ [2][16][64].
__global__ __launch_bounds__(256) void k_gram(const ushort* __restrict__ Q,
                                              const ushort* __restrict__ K,
                                              float* __restrict__ G,
                                              float* __restrict__ SQ) {
  __shared__ ushort Xt[64][72];   // [c][n] bf16
  int ns = blockIdx.x, qk = blockIdx.y, bh = blockIdx.z;
  const ushort* src = (qk ? K : Q) + (size_t)bh * NHW * 64;
  int t = threadIdx.x, lane = t & 63, wv = t >> 6;
  int lr = lane & 15, lg = lane >> 4;
  int ci0 = (wv >> 1) * 32, cj0 = (wv & 1) * 32;
  f32x4 acc[2][2];
#pragma unroll
  for (int i = 0; i < 2; ++i)
#pragma unroll
    for (int j = 0; j < 2; ++j) acc[i][j] = (f32x4){0.f, 0.f, 0.f, 0.f};
  float sq = 0.f;
  for (int it = 0; it < 4; ++it) {
    __syncthreads();
#pragma unroll
    for (int i2 = 0; i2 < 2; ++i2) {
      int n = t & 63, cg = (t >> 6) + 4 * i2;
      union { bf16x8 v; ushort u[8]; } ld;
      ld.v = *(const bf16x8*)&src[((size_t)cg * NHW + ns * 256 + it * 64 + n) * 8];
#pragma unroll
      for (int j = 0; j < 8; ++j) Xt[cg * 8 + j][n] = ld.u[j];
    }
    __syncthreads();
    if (t < 64) {
#pragma unroll
      for (int g = 0; g < 8; ++g) {
        union { bf16x8 v; ushort u[8]; } rd;
        rd.v = *(const bf16x8*)&Xt[t][g * 8];
#pragma unroll
        for (int j = 0; j < 8; ++j) sq += bf2f(rd.u[j]);
      }
    }
#pragma unroll
    for (int kh = 0; kh < 2; ++kh) {
      bf16x8 a0 = *(const bf16x8*)&Xt[ci0 + lr][kh * 32 + lg * 8];
      bf16x8 a1 = *(const bf16x8*)&Xt[ci0 + 16 + lr][kh * 32 + lg * 8];
      bf16x8 b0 = *(const bf16x8*)&Xt[cj0 + lr][kh * 32 + lg * 8];
      bf16x8 b1 = *(const bf16x8*)&Xt[cj0 + 16 + lr][kh * 32 + lg * 8];
      acc[0][0] = __builtin_amdgcn_mfma_f32_16x16x32_bf16(a0, b0, acc[0][0], 0, 0, 0);
      acc[0][1] = __builtin_amdgcn_mfma_f32_16x16x32_bf16(a0, b1, acc[0][1], 0, 0, 0);
      acc[1][0] = __builtin_amdgcn_mfma_f32_16x16x32_bf16(a1, b0, acc[1][0], 0, 0, 0);
      acc[1][1] = __builtin_amdgcn_mfma_f32_16x16x32_bf16(a1, b1, acc[1][1], 0, 0, 0);
    }
  }
  float* g = G + ((size_t)qk * NBH + bh) * 4096;
#pragma unroll
  for (int ii = 0; ii < 2; ++ii)
#pragma unroll
    for (int jj = 0; jj < 2; ++jj)
#pragma unroll
      for (int r = 0; r < 4; ++r)
        atomicAdd(&g[(ci0 + ii * 16 + lg * 4 + r) * 64 + cj0 + jj * 16 + lr], acc[ii][jj][r]);
  if (t < 64) atomicAdd(&SQ[((size_t)qk * NBH + bh) * 64 + t], sq);
}

// ---------------- per-(b,h) exp2 scale (parallel reduce) ----------------
__global__ __launch_bounds__(256) void k_scale(const float* __restrict__ G,
                                               const float* __restrict__ SQ,
                                               float* __restrict__ SC) {
  __shared__ float red[256];
  int bh = blockIdx.x, t = threadIdx.x;
  float ssum = 0.f;
  for (int i = t; i < 4096; i += 256)
    ssum += G[(size_t)bh * 4096 + i] * G[(size_t)(NBH + bh) * 4096 + i];
  red[t] = ssum;
  __syncthreads();
  if (t < 128) red[t] += red[t + 128];
  __syncthreads();
  if (t < 64) {
    float v = red[t] + red[t + 64];
    float v2 = SQ[bh * 64 + t] * SQ[(NBH + bh) * 64 + t];
#pragma unroll
    for (int m = 32; m; m >>= 1) { v += __shfl_xor(v, m); v2 += __shfl_xor(v2, m); }
    if (t == 0) {
      const double N2 = (double)NHW * (double)NHW;
      double mean = (double)v2 / (N2 * 48.0);
      double ea2 = (double)v / (N2 * 2304.0);
      double var = ea2 - mean * mean;
      SC[bh] = (float)((1.0 / sqrt(var + 1e-5)) / 48.0 * 1.4426950408889634);
    }
  }
}

// ---------------- flash attention v8: 2-tile unroll for in-wave ILP ----------------
// grid (1152); block p -> XCD p%8; XCD g owns bh {2g,2g+1}. 4 waves x 32 q-rows.
// 4 LDS buffers; per 2-tile iter: vmcnt(0)[only needed loads]; barrier; stage(t+2,t+3);
// compute(t), compute(t+1) — independent S/P streams, shared O accumulators.
__global__ __launch_bounds__(256, 2) void k_attn(const ushort* __restrict__ Q,
                                                 const ushort* __restrict__ K,
                                                 const ushort* __restrict__ V,
                                                 const float* __restrict__ SC,
                                                 ushort* __restrict__ OHp,
                                                 float* __restrict__ Lp) {
  __shared__ ushort Kl[4][2048];
  __shared__ ushort Vl[4][2048];
  int p = blockIdx.x;
  int gb = p & 7;
  int w = p >> 3;          // 0..143
  int qt = w % 18;
  int rem = w / 18;        // 0..7
  int chunk = rem & 3;
  int bh = gb * 2 + (rem >> 2);
  int t = threadIdx.x, lane = t & 63, wv = t >> 6;
  int ql = lane & 31, h = lane >> 5;
  int q0 = qt * 128 + wv * 32;
  int m00 = chunk * CHUNK;
  const ushort* base = Q + (size_t)bh * NHW * 64;
  float sc2 = SC[bh];

  bf16x8 qfr[4];
#pragma unroll
  for (int kc = 0; kc < 4; ++kc)
    qfr[kc] = *(const bf16x8*)&base[((size_t)(kc * 2 + h) * NHW + q0 + ql) * 8];
  asm volatile("s_waitcnt vmcnt(0)" ::: "memory");

  const ushort* kst = K + (size_t)bh * NHW * 64 + ((size_t)(wv * 2 + h) * NHW + m00 + ql) * 8;
  const ushort* vst = V + (size_t)bh * NHW * 64 + ((size_t)((m00 >> 3) + wv) * 64 + lane) * 8;

  f32x16 o0 = {}, o1 = {};
  float lpA = 0.f, lpB = 0.f;

  auto STAGE = [&](int tt) {
    gload16(kst + (size_t)tt * 256, (void*)&Kl[tt & 3][wv * 512]);
    gload16(vst + (size_t)tt * 2048, (void*)&Vl[tt & 3][wv * 512]);
  };
  auto COMPUTE = [&](int cb, float& lpr) {
    bf16x8 ka[4], vb[4];
#pragma unroll
    for (int i = 0; i < 4; ++i)
      ka[i] = *(const bf16x8*)&Kl[cb][(2 * i + h) * 256 + ql * 8];
    vb[0] = *(const bf16x8*)&Vl[cb][h * 512 + ql * 8];
    vb[1] = *(const bf16x8*)&Vl[cb][(2 + h) * 512 + ql * 8];
    vb[2] = *(const bf16x8*)&Vl[cb][h * 512 + (ql + 32) * 8];
    vb[3] = *(const bf16x8*)&Vl[cb][(2 + h) * 512 + (ql + 32) * 8];
    __builtin_amdgcn_s_setprio(1);
    f32x16 s = {};
    s = __builtin_amdgcn_mfma_f32_32x32x16_bf16(ka[0], qfr[0], s, 0, 0, 0);
    s = __builtin_amdgcn_mfma_f32_32x32x16_bf16(ka[1], qfr[1], s, 0, 0, 0);
    s = __builtin_amdgcn_mfma_f32_32x32x16_bf16(ka[2], qfr[2], s, 0, 0, 0);
    s = __builtin_amdgcn_mfma_f32_32x32x16_bf16(ka[3], qfr[3], s, 0, 0, 0);
    __builtin_amdgcn_s_setprio(0);
    float pv[16];
    float l0 = 0.f, l1 = 0.f, l2 = 0.f, l3 = 0.f;
#pragma unroll
    for (int r = 0; r < 16; r += 4) {
      pv[r] = __builtin_exp2f(s[r] * sc2);
      pv[r + 1] = __builtin_exp2f(s[r + 1] * sc2);
      pv[r + 2] = __builtin_exp2f(s[r + 2] * sc2);
      pv[r + 3] = __builtin_exp2f(s[r + 3] * sc2);
      l0 += pv[r]; l1 += pv[r + 1]; l2 += pv[r + 2]; l3 += pv[r + 3];
    }
    lpr += (l0 + l1) + (l2 + l3);
    uint u[8];
#pragma unroll
    for (int i = 0; i < 8; ++i)
      asm("v_cvt_pk_bf16_f32 %0, %1, %2" : "=v"(u[i]) : "v"(pv[2 * i]), "v"(pv[2 * i + 1]));
    asm volatile("v_permlane32_swap_b32 %0, %1" : "+v"(u[0]), "+v"(u[2]));
    asm volatile("v_permlane32_swap_b32 %0, %1" : "+v"(u[1]), "+v"(u[3]));
    asm volatile("v_permlane32_swap_b32 %0, %1" : "+v"(u[4]), "+v"(u[6]));
    asm volatile("v_permlane32_swap_b32 %0, %1" : "+v"(u[5]), "+v"(u[7]));
    union { uint uu[4]; bf16x8 v; } pa0, pa1;
    pa0.uu[0] = u[0]; pa0.uu[1] = u[1]; pa0.uu[2] = u[2]; pa0.uu[3] = u[3];
    pa1.uu[0] = u[4]; pa1.uu[1] = u[5]; pa1.uu[2] = u[6]; pa1.uu[3] = u[7];
    __builtin_amdgcn_s_setprio(1);
    o0 = __builtin_amdgcn_mfma_f32_32x32x16_bf16(pa0.v, vb[0], o0, 0, 0, 0);
    o0 = __builtin_amdgcn_mfma_f32_32x32x16_bf16(pa1.v, vb[1], o0, 0, 0, 0);
    o1 = __builtin_amdgcn_mfma_f32_32x32x16_bf16(pa0.v, vb[2], o1, 0, 0, 0);
    o1 = __builtin_amdgcn_mfma_f32_32x32x16_bf16(pa1.v, vb[3], o1, 0, 0, 0);
    __builtin_amdgcn_s_setprio(0);
  };

  // prologue: stage tiles 0,1
  STAGE(0); STAGE(1);
  for (int mt = 0; mt < NT; mt += 2) {
    asm volatile("s_waitcnt vmcnt(0)" ::: "memory");
    __builtin_amdgcn_s_barrier();
    if (mt + 2 < NT) { STAGE(mt + 2); STAGE(mt + 3); }
    COMPUTE(mt & 3, lpA);
    COMPUTE((mt + 1) & 3, lpB);
  }

  float lp = lpA + lpB;
  lp += __shfl_xor(lp, 32);
  if (h == 0) Lp[(size_t)(chunk * NBH + bh) * NHW + q0 + ql] = lp;
  ushort* od = OHp + ((size_t)(chunk * NBH + bh) * NHW + q0) * 64;
#pragma unroll
  for (int r = 0; r < 16; ++r) {
    int qrow = (r & 3) + 8 * (r >> 2) + 4 * h;
    od[(size_t)qrow * 64 + ql] = f2bf(o0[r]);
    od[(size_t)qrow * 64 + 32 + ql] = f2bf(o1[r]);
  }
}

// ---------------- combine partials + head-mean + projection + residual ----------------
__global__ __launch_bounds__(256) void k_proj(const ushort* __restrict__ OHp,
                                              const float* __restrict__ Lp,
                                              const float* __restrict__ PW,
                                              const float* __restrict__ PB,
                                              const float* __restrict__ org,
                                              float* __restrict__ out) {
  __shared__ float Ls[4][4][16];
  __shared__ float linv[4][16];
  __shared__ float Ms[64][17];
  int p0 = blockIdx.x * 16, b = blockIdx.y;
  int t = threadIdx.x;
  {
    int ck = t >> 6, hd = (t >> 4) & 3, p = t & 15;
    Ls[ck][hd][p] = Lp[(size_t)(ck * NBH + b * 4 + hd) * NHW + p0 + p];
  }
  __syncthreads();
  if (t < 64) {
    int hd = t >> 4, p = t & 15;
    linv[hd][p] = 1.f / (Ls[0][hd][p] + Ls[1][hd][p] + Ls[2][hd][p] + Ls[3][hd][p]);
  }
  __syncthreads();
  {
    int p = t >> 4, c4 = (t & 15) * 4;
    float a0 = 0.f, a1 = 0.f, a2 = 0.f, a3 = 0.f;
#pragma unroll
    for (int hd = 0; hd < 4; ++hd) {
      float s0 = 0.f, s1 = 0.f, s2 = 0.f, s3 = 0.f;
#pragma unroll
      for (int ck = 0; ck < 4; ++ck) {
        ushort4 u = *(const ushort4*)&OHp[((size_t)(ck * NBH + b * 4 + hd) * NHW + p0 + p) * 64 + c4];
        s0 += bf2f(u.x); s1 += bf2f(u.y); s2 += bf2f(u.z); s3 += bf2f(u.w);
      }
      float li = linv[hd][p];
      a0 += s0 * li; a1 += s1 * li; a2 += s2 * li; a3 += s3 * li;
    }
    Ms[c4][p] = 0.25f * a0;
    Ms[c4 + 1][p] = 0.25f * a1;
    Ms[c4 + 2][p] = 0.25f * a2;
    Ms[c4 + 3][p] = 0.25f * a3;
  }
  __syncthreads();
  int p = t & 15, og = t >> 4;
  float acc[4];
#pragma unroll
  for (int i = 0; i < 4; ++i) acc[i] = PB[og * 4 + i];
  for (int c = 0; c < 64; ++c) {
    float xr = Ms[c][p];
#pragma unroll
    for (int i = 0; i < 4; ++i) acc[i] += PW[(og * 4 + i) * 64 + c] * xr;
  }
  const float* orgp = org + (size_t)b * NC * NHW + p0 + p;
  float* outp = out + (size_t)b * NC * NHW + p0 + p;
#pragma unroll
  for (int i = 0; i < 4; ++i) {
    int oc = og * 4 + i;
    outp[(size_t)oc * NHW] = orgp[(size_t)oc * NHW] + acc[i];
  }
}

extern "C" void kernel_launch(void* const* d_in, const int* in_sizes, int n_in,
                              void* d_out, int out_size, void* d_ws, size_t ws_size,
                              hipStream_t stream) {
  const float* emb = (const float*)d_in[0];
  const float* lnw = (const float*)d_in[1];
  const float* lnb = (const float*)d_in[2];
  const float* wq  = (const float*)d_in[3];
  const float* wk  = (const float*)d_in[4];
  const float* wv  = (const float*)d_in[5];
  const float* dwq = (const float*)d_in[6];
  const float* dwk = (const float*)d_in[7];
  const float* dwv = (const float*)d_in[8];
  const float* pw  = (const float*)d_in[9];
  const float* pb  = (const float*)d_in[10];
  char* ws = (char*)d_ws;
  ushort* Y   = (ushort*)(ws + OB_Y);
  float*  G   = (float*)(ws + OB_G);
  float*  SQ  = (float*)(ws + OB_SQ);
  ushort* OHp = (ushort*)(ws + OB_OHP);
  ushort* Qb  = (ushort*)(ws + OB_Q);
  ushort* Kb  = (ushort*)(ws + OB_K);
  ushort* Vb  = (ushort*)(ws + OB_V);
  float*  Lpt = (float*)(ws + OB_L);
  float*  SCp = (float*)(ws + OB_SC);
  float* out = (float*)d_out;

  k_lnconv<<<dim3(NHW / 64, NB, 3), 256, 0, stream>>>(emb, lnw, lnb, wq, wk, wv, Y);
  k_dw<<<dim3(NH, 12, NB), 256, 0, stream>>>(Y, dwq, dwk, dwv, Qb, Kb, Vb);
  hipMemsetAsync(G, 0, 532480, stream);
  k_gram<<<dim3(9, 2, NBH), 256, 0, stream>>>(Qb, Kb, G, SQ);
  k_scale<<<dim3(NBH), 256, 0, stream>>>(G, SQ, SCp);
  k_attn<<<dim3(1152), 256, 0, stream>>>(Qb, Kb, Vb, SCp, OHp, Lpt);
  k_proj<<<dim3(NHW / 16, NB), 256, 0, stream>>>(OHp, Lpt, pw, pb, emb, out);
}